// Round 7
// baseline (317.574 us; speedup 1.0000x reference)
//
#include <hip/hip_runtime.h>

// Problem constants: B=2, N=2048, C=512, H=8, HD=64
// Inputs fp32 (per reference); intermediates bf16 in ws; output fp32.
typedef __attribute__((ext_vector_type(8))) short bf16x8;
typedef __attribute__((ext_vector_type(4))) short bf16x4;
typedef __attribute__((ext_vector_type(4))) float f32x4;

__device__ __forceinline__ float bf2f(unsigned short u) {
  union { unsigned int i; float f; } c; c.i = ((unsigned int)u) << 16; return c.f;
}
__device__ __forceinline__ unsigned short f2bf(float x) {
  union { float f; unsigned int i; } c; c.f = x;
  return (unsigned short)((c.i + 0x7fffu + ((c.i >> 16) & 1u)) >> 16);
}
__device__ __forceinline__ unsigned int pk2(float a, float b) {
  return (unsigned int)f2bf(a) | ((unsigned int)f2bf(b) << 16);
}

__device__ __forceinline__ uint4 ld8f(const float* p) {
  const float4 a = *(const float4*)p;
  const float4 b = *(const float4*)(p + 4);
  uint4 r;
  r.x = (unsigned)f2bf(a.x) | ((unsigned)f2bf(a.y) << 16);
  r.y = (unsigned)f2bf(a.z) | ((unsigned)f2bf(a.w) << 16);
  r.z = (unsigned)f2bf(b.x) | ((unsigned)f2bf(b.y) << 16);
  r.w = (unsigned)f2bf(b.z) | ((unsigned)f2bf(b.w) << 16);
  return r;
}

// Async global->LDS, 16B per lane: HW writes lds_base + lane*16.
__device__ __forceinline__ void gload16(const unsigned short* g, short* l) {
  __builtin_amdgcn_global_load_lds((const __attribute__((address_space(1))) void*)g,
                                   (__attribute__((address_space(3))) void*)l, 16, 0, 0);
}

// fp32 -> bf16 pre-convert of x, pe, Wqkv, Wpos, Wproj (R11-proven).
__global__ __launch_bounds__(256) void k_cvt(const float* __restrict__ x,
    const float* __restrict__ pe, const float* __restrict__ wq,
    const float* __restrict__ wp, const float* __restrict__ wj,
    unsigned short* __restrict__ dst) {
  const long long i8 = ((long long)blockIdx.x * 256 + threadIdx.x) * 8;
  const float* src; long long off;
  if (i8 < 2097152)      { src = x;  off = i8; }
  else if (i8 < 4194304) { src = pe; off = i8 - 2097152; }
  else if (i8 < 4980736) { src = wq; off = i8 - 4194304; }
  else if (i8 < 5242880) { src = wp; off = i8 - 4980736; }
  else                   { src = wj; off = i8 - 5242880; }
  *(uint4*)&dst[i8] = ld8f(src + off);
}

// 128x128 NT GEMM mainloop (m97 ladder): 256 threads = 2x2 waves, each wave a
// 64x64 subtile (4x4 MFMA 16x16x32). Staging via global_load_lds width=16.
__device__ __forceinline__ void gemm128_mainloop(const unsigned short* __restrict__ Arow,
                                                 const unsigned short* __restrict__ Wrow,
                                                 short* Asl, short* Wsl, f32x4 acc[4][4]) {
  const int tid = threadIdx.x, w = tid >> 6, lane = tid & 63, lm = lane & 15, lq = lane >> 4;
  const int wm = w >> 1, wn = w & 1;
  const int lrow = lane >> 3;                       // 0..7 within an 8-row slab
  const int gcol = (((lane & 7) ^ lrow) * 8);       // swizzled source chunk
#pragma unroll
  for (int mt = 0; mt < 4; ++mt)
#pragma unroll
    for (int nt = 0; nt < 4; ++nt) acc[mt][nt] = (f32x4){0.f, 0.f, 0.f, 0.f};
#pragma unroll 1
  for (int kc = 0; kc < 512; kc += 64) {
    __syncthreads();  // prior iteration's frag reads done
#pragma unroll
    for (int ld = 0; ld < 4; ++ld) {
      const int rbase = w * 32 + ld * 8;
      gload16(&Arow[(size_t)(rbase + lrow) * 512 + kc + gcol], &Asl[rbase * 64]);
      gload16(&Wrow[(size_t)(rbase + lrow) * 512 + kc + gcol], &Wsl[rbase * 64]);
    }
    __syncthreads();  // staging visible (vmcnt drained by barrier)
#pragma unroll
    for (int kk = 0; kk < 2; ++kk) {
      const int pcs = ((kk * 4 + lq) ^ (lm & 7)) * 8;
      bf16x8 af[4], bfr[4];
#pragma unroll
      for (int mt = 0; mt < 4; ++mt)
        af[mt] = *(const bf16x8*)&Asl[(wm * 64 + mt * 16 + lm) * 64 + pcs];
#pragma unroll
      for (int nt = 0; nt < 4; ++nt)
        bfr[nt] = *(const bf16x8*)&Wsl[(wn * 64 + nt * 16 + lm) * 64 + pcs];
#pragma unroll
      for (int mt = 0; mt < 4; ++mt)
#pragma unroll
        for (int nt = 0; nt < 4; ++nt)
          acc[mt][nt] = __builtin_amdgcn_mfma_f32_16x16x32_bf16(af[mt], bfr[nt], acc[mt][nt], 0, 0, 0);
    }
  }
}

// Coalesced epilogue via LDS transpose buffer TT[128][130] bf16 (aliases the
// GEMM staging LDS). Phase A: acc (+optional bias, fp32 add BEFORE rounding)
// -> TT[m_local][cc_local]. Phase B: uint4 rows to dst[bh][n][d].
__device__ __forceinline__ void epi_rows(const f32x4 acc[4][4], const float* __restrict__ bias,
                                         short* TT, unsigned short* __restrict__ dst,
                                         int m0, int cc0) {
  const int tid = threadIdx.x, w = tid >> 6, lane = tid & 63, lm = lane & 15, lq = lane >> 4;
  const int wm = w >> 1, wn = w & 1;
  __syncthreads();  // prior LDS use (mainloop frags / previous phase B) done
#pragma unroll
  for (int mt = 0; mt < 4; ++mt)
#pragma unroll
    for (int nt = 0; nt < 4; ++nt) {
      const int ccl = wn * 64 + nt * 16 + lm;
      const float bb = bias ? bias[(cc0 + ccl) & 511] : 0.f;
#pragma unroll
      for (int r = 0; r < 4; ++r)
        TT[(wm * 64 + mt * 16 + lq * 4 + r) * 130 + ccl] = (short)f2bf(acc[mt][nt][r] + bb);
    }
  __syncthreads();  // TT visible
#pragma unroll
  for (int rr = 0; rr < 8; ++rr) {
    const int ml = rr * 16 + (tid >> 4), ccl = (tid & 15) * 8;
    const uint4 v = *(const uint4*)&TT[ml * 130 + ccl];
    const int m = m0 + ml, b = m >> 11, n = m & 2047;
    const int cc = cc0 + ccl, hh = (cc >> 6) & 7, d = cc & 63;
    *(uint4*)&dst[((size_t)(b * 8 + hh) * 2048 + n) * 64 + d] = v;
  }
}

// Transposed epilogue for the V section: TT[m][cc] read along m, emit
// vt[bh][d][n] rows (coalesced). Fuses the old k_transpose_v kernel.
__device__ __forceinline__ void epi_cols(const f32x4 acc[4][4], short* TT,
                                         unsigned short* __restrict__ vt,
                                         int m0, int cc0) {
  const int tid = threadIdx.x, w = tid >> 6, lane = tid & 63, lm = lane & 15, lq = lane >> 4;
  const int wm = w >> 1, wn = w & 1;
  __syncthreads();
#pragma unroll
  for (int mt = 0; mt < 4; ++mt)
#pragma unroll
    for (int nt = 0; nt < 4; ++nt) {
      const int ccl = wn * 64 + nt * 16 + lm;
#pragma unroll
      for (int r = 0; r < 4; ++r)
        TT[(wm * 64 + mt * 16 + lq * 4 + r) * 130 + ccl] = (short)f2bf(acc[mt][nt][r]);
    }
  __syncthreads();
  const int b = m0 >> 11;
#pragma unroll
  for (int ss = 0; ss < 8; ++ss) {
    const int ccl = ss * 16 + (tid >> 4), mch = (tid & 15) * 8;
    alignas(16) unsigned short tmp[8];
#pragma unroll
    for (int j = 0; j < 8; ++j) tmp[j] = (unsigned short)TT[(mch + j) * 130 + ccl];
    const int cc = cc0 + ccl, hh = (cc >> 6) & 7, d = cc & 63;
    const int n = (m0 & 2047) + mch;
    *(uint4*)&vt[((size_t)(b * 8 + hh) * 64 + d) * 2048 + n] = *(const uint4*)tmp;
  }
}

// Fused 128-tile: qkv = x @ Wqkv^T (cc0 < 1536) and pos = pe @ Wpos^T.
// sec 0 -> qu/qv (two bias passes), 1 -> k, 2 -> V transposed direct to vt,
// 3 -> pos. All stores coalesced via TT.
__global__ __launch_bounds__(256) void k_gemm_qkvpos(const unsigned short* __restrict__ xb,
    const unsigned short* __restrict__ peb, const unsigned short* __restrict__ wqb,
    const unsigned short* __restrict__ wpb, const float* __restrict__ ub,
    const float* __restrict__ vb, unsigned short* __restrict__ qu,
    unsigned short* __restrict__ qv, unsigned short* __restrict__ kg,
    unsigned short* __restrict__ vt, unsigned short* __restrict__ pos) {
  __shared__ short SB[16640];  // mainloop: A[0:8192)+W[8192:16384); epi: TT[128][130]
  f32x4 acc[4][4];
  const int m0 = blockIdx.y * 128, cc0 = blockIdx.x * 128;
  const unsigned short* Arow = (cc0 < 1536 ? xb : peb) + (size_t)m0 * 512;
  const unsigned short* Wrow = (cc0 < 1536) ? (wqb + (size_t)cc0 * 512)
                                            : (wpb + (size_t)(cc0 - 1536) * 512);
  gemm128_mainloop(Arow, Wrow, SB, SB + 8192, acc);
  const int sec = cc0 >> 9;  // block-uniform (cc0 multiple of 128)
  if (sec == 0) {
    epi_rows(acc, ub, SB, qu, m0, cc0);
    epi_rows(acc, vb, SB, qv, m0, cc0);
  } else if (sec == 1) {
    epi_rows(acc, nullptr, SB, kg, m0, cc0);
  } else if (sec == 2) {
    epi_cols(acc, SB, vt, m0, cc0);
  } else {
    epi_rows(acc, nullptr, SB, pos, m0, cc0);
  }
}

// Fused flash attention v8 — v6 data layout & numerics, re-phased to 2
// barriers/tile (was 3) via register preload of all compute-phase operands.
// Per tile: (a) frag preload K/V/Pn from LDS -> regs; S_a; (b) staging writes
// for jt+1 + global prefetch jt+2 (overlaps (c) on other waves); (c) QK^T +
// T-build from REGS -> T stores; S_b; (d) gather+exp+pack; (e) PV from reg V.
// Hazards: (b) writes vs (a) reads -> S_a; next (a) reads vs (b) writes ->
// S_b; T single-buffer safe (next T writes behind S_a(jt+1), which waits for
// all waves' gather). Pn window aliasing identical to v6 (aliased slot feeds
// never-read T cols). Numerics byte-identical to v6.
__global__ __launch_bounds__(512, 4) void k_flash(const unsigned short* __restrict__ qu,
    const unsigned short* __restrict__ qv, const unsigned short* __restrict__ kg,
    const unsigned short* __restrict__ vt, const unsigned short* __restrict__ posg,
    unsigned short* __restrict__ og) {
  // LDS (shorts): Ks[64][72] K-tile [k][d]; Vs[64][72] V-tile [d][j];
  // Pn[128][72] circular pos window; T[65][84] pos-products [q-local][c].
  __shared__ short SB[23892];
  short* Ks = SB;
  short* Vs = SB + 4608;
  short* Pn = SB + 9216;
  short* T  = SB + 18432;
  float* Ored = (float*)SB;  // epilogue alias: [65][68] f32, row 64 = lsum
  const int tid = threadIdx.x, w = tid >> 6, lane = tid & 63, lm = lane & 15, lq = lane >> 4;
  const int wk = w & 3;   // k-slice within tile
  const int h  = w >> 2;  // q-half (stripes {2h, 2h+1})
  const int sw = w >> 1;  // T-build stripe
  const int ph = w & 1;   // T-build phase-half
  // XCD-aware remap (bijective on [0,512)): hw&7 = XCD; each XCD owns bh pair
  // {2*xcd, 2*xcd+1} with all 32 i-tiles -> per-XCD working set ~2.5MB < 4MB L2.
  const int hw = blockIdx.x + 32 * blockIdx.y;
  const int xcd = hw & 7, idx = hw >> 3;
  const int bh = xcd * 2 + (idx & 1);
  const int i0 = (idx >> 1) * 64;
  const size_t bhs = (size_t)bh;
  const unsigned short* qub = qu + bhs * (2048 * 64);
  const unsigned short* qvb = qv + bhs * (2048 * 64);
  const unsigned short* pob = posg + bhs * (2048 * 64);
  // (q+u) B-frags for this wave's two q-stripes (content scores).
  bf16x8 au[2][2];
#pragma unroll
  for (int qt = 0; qt < 2; ++qt) {
    const int qs = h * 2 + qt;
    au[qt][0] = *(const bf16x8*)&qub[(size_t)(i0 + qs * 16 + lm) * 64 + lq * 8];
    au[qt][1] = *(const bf16x8*)&qub[(size_t)(i0 + qs * 16 + lm) * 64 + 32 + lq * 8];
  }
  // (q+v) frags for T-build stripe sw, and edge rows (T row 64 = q_{i0+64}).
  const bf16x8 av0 = *(const bf16x8*)&qvb[(size_t)(i0 + sw * 16 + lm) * 64 + lq * 8];
  const bf16x8 av1 = *(const bf16x8*)&qvb[(size_t)(i0 + sw * 16 + lm) * 64 + 32 + lq * 8];
  const int rowe = min(i0 + 49 + lm, 2047);  // row 64 never read when i0==1984
  const bf16x8 ae0 = *(const bf16x8*)&qvb[(size_t)rowe * 64 + lq * 8];
  const bf16x8 ae1 = *(const bf16x8*)&qvb[(size_t)rowe * 64 + 32 + lq * 8];
  float lsum[2] = {0.f, 0.f};  // q = (h*2+qt)*16+lm, own k-slice partial
  f32x4 oacc[2][4];            // [qt][dt]: q=i0+(h*2+qt)*16+lq*4+r, d=dt*16+lm
#pragma unroll
  for (int ii = 0; ii < 2; ++ii)
#pragma unroll
    for (int jj = 0; jj < 4; ++jj) oacc[ii][jj] = (f32x4){0.f, 0.f, 0.f, 0.f};
  const int krow = tid >> 3, kc8 = (tid & 7) * 8;  // 512 threads = 64 rows x 8 chunks
  const int pb0 = 1983 - i0;
  // Prologue: stage tile 0 (K/V + full 128-row pos window), then prefetch the
  // operands that iter 0's step (b) will write (tile 1 K/V, pos rows +128).
  {
    uint4 kr = *(const uint4*)&kg[(bhs * 2048 + krow) * 64 + kc8];
    uint4 vr = *(const uint4*)&vt[(bhs * 64 + krow) * 2048 + kc8];
    uint4 p0 = *(const uint4*)&pob[(size_t)((pb0 + krow + 4096) & 2047) * 64 + kc8];
    uint4 p1 = *(const uint4*)&pob[(size_t)((pb0 + 64 + krow + 4096) & 2047) * 64 + kc8];
    *(uint4*)&Ks[krow * 72 + kc8] = kr;
    *(uint4*)&Vs[krow * 72 + kc8] = vr;
    *(uint4*)&Pn[((pb0 + krow) & 127) * 72 + kc8] = p0;
    *(uint4*)&Pn[((pb0 + 64 + krow) & 127) * 72 + kc8] = p1;
  }
  uint4 kr = *(const uint4*)&kg[(bhs * 2048 + 64 + krow) * 64 + kc8];
  uint4 vr = *(const uint4*)&vt[(bhs * 64 + krow) * 2048 + 64 + kc8];
  uint4 pr0 = *(const uint4*)&pob[(size_t)((pb0 + 128 + krow + 4096) & 2047) * 64 + kc8];
  __syncthreads();  // staging(0) visible
#pragma unroll 1
  for (int jt = 0; jt < 32; ++jt) {
    const int j0 = jt * 64;
    const int pb = pb0 + j0;
    // (a) frag preload for THIS tile: K, V, Pn -> registers.
    const bf16x8 k0 = *(const bf16x8*)&Ks[(wk * 16 + lm) * 72 + lq * 8];
    const bf16x8 k1 = *(const bf16x8*)&Ks[(wk * 16 + lm) * 72 + 32 + lq * 8];
    bf16x4 vf[4];
#pragma unroll
    for (int dt = 0; dt < 4; ++dt)
      vf[dt] = *(const bf16x4*)&Vs[(dt * 16 + lm) * 72 + wk * 16 + lq * 4];
    const int sbase = 49 - sw * 16;
    bf16x8 pnf[3][2];
    if (ph == 0) {
#pragma unroll
      for (int ct = 0; ct < 3; ++ct) {
        const int slot = (pb + sbase + ct * 16 + lm) & 127;
        pnf[ct][0] = *(const bf16x8*)&Pn[slot * 72 + lq * 8];
        pnf[ct][1] = *(const bf16x8*)&Pn[slot * 72 + 32 + lq * 8];
      }
    } else {
#pragma unroll
      for (int ct = 3; ct < 5; ++ct) {
        const int slot = (pb + sbase + ct * 16 + lm) & 127;
        pnf[ct - 3][0] = *(const bf16x8*)&Pn[slot * 72 + lq * 8];
        pnf[ct - 3][1] = *(const bf16x8*)&Pn[slot * 72 + 32 + lq * 8];
      }
      const int slot = (pb + sw * 16 + lm) & 127;
      pnf[2][0] = *(const bf16x8*)&Pn[slot * 72 + lq * 8];
      pnf[2][1] = *(const bf16x8*)&Pn[slot * 72 + 32 + lq * 8];
    }
    __syncthreads();  // S_a: all frag reads of staging(jt) done
    // (b) staging writes for tile jt+1; global prefetch for tile jt+2.
    if (jt < 31) {
      *(uint4*)&Ks[krow * 72 + kc8] = kr;
      *(uint4*)&Vs[krow * 72 + kc8] = vr;
      *(uint4*)&Pn[((pb + 128 + krow) & 127) * 72 + kc8] = pr0;
      if (jt < 30) {
        const int jn = j0 + 128;
        kr = *(const uint4*)&kg[(bhs * 2048 + jn + krow) * 64 + kc8];
        vr = *(const uint4*)&vt[(bhs * 64 + krow) * 2048 + jn + kc8];
        pr0 = *(const uint4*)&pob[(size_t)((pb + 192 + krow + 4096) & 2047) * 64 + kc8];
      }
    }
    // (c) Content scores (regs): cacc[qt][r] =
    //   (q_{i0+(h*2+qt)*16+lm}+u) . K_{j0+wk*16+lq*4+r}
    f32x4 cacc[2];
#pragma unroll
    for (int qt = 0; qt < 2; ++qt) {
      cacc[qt] = __builtin_amdgcn_mfma_f32_16x16x32_bf16(k0, au[qt][0], (f32x4){0.f,0.f,0.f,0.f}, 0, 0, 0);
      cacc[qt] = __builtin_amdgcn_mfma_f32_16x16x32_bf16(k1, au[qt][1], cacc[qt], 0, 0, 0);
    }
    // T build from reg-held pos frags: stripe sw rows qg=sw*16+lm, cols by ph.
    // T[qg][c] = (q_{i0+qg}+v) . pos_{(pb + c + 49 - 16*sw) mod 2048}
    if (ph == 0) {
#pragma unroll
      for (int ct = 0; ct < 3; ++ct) {
        f32x4 t0 = __builtin_amdgcn_mfma_f32_16x16x32_bf16(pnf[ct][0], av0, (f32x4){0.f,0.f,0.f,0.f}, 0, 0, 0);
        t0 = __builtin_amdgcn_mfma_f32_16x16x32_bf16(pnf[ct][1], av1, t0, 0, 0, 0);
        uint2 pk; pk.x = pk2(t0[0], t0[1]); pk.y = pk2(t0[2], t0[3]);
        *(uint2*)&T[(sw * 16 + lm) * 84 + ct * 16 + lq * 4] = pk;
      }
    } else {
#pragma unroll
      for (int ct = 3; ct < 5; ++ct) {
        f32x4 t0 = __builtin_amdgcn_mfma_f32_16x16x32_bf16(pnf[ct - 3][0], av0, (f32x4){0.f,0.f,0.f,0.f}, 0, 0, 0);
        t0 = __builtin_amdgcn_mfma_f32_16x16x32_bf16(pnf[ct - 3][1], av1, t0, 0, 0, 0);
        uint2 pk; pk.x = pk2(t0[0], t0[1]); pk.y = pk2(t0[2], t0[3]);
        *(uint2*)&T[(sw * 16 + lm) * 84 + ct * 16 + lq * 4] = pk;
      }
      {  // edge row qg=64: T[64][c'] = (q_{i0+64}+v) . pos_{pb + c'};
         // ph1 waves cover col groups c' = sw*16 + 0..15.
        f32x4 e0 = __builtin_amdgcn_mfma_f32_16x16x32_bf16(pnf[2][0], ae0, (f32x4){0.f,0.f,0.f,0.f}, 0, 0, 0);
        e0 = __builtin_amdgcn_mfma_f32_16x16x32_bf16(pnf[2][1], ae1, e0, 0, 0, 0);
        if (lm == 15) {
          uint2 pk; pk.x = pk2(e0[0], e0[1]); pk.y = pk2(e0[2], e0[3]);
          *(uint2*)&T[64 * 84 + sw * 16 + lq * 4] = pk;
        }
      }
    }
    __syncthreads();  // S_b: T visible; staging(jt+1) visible
    // (d) Gather pos addend + softmax-exp + in-lane bf16 pack (PV A-frags).
    const int diag = i0 - j0;
    const int jl0 = wk * 16 + lq * 4;
    bf16x4 pf[2];
    if (diag >= 64 || diag <= -128) {  // fast: delta uniform, no j==i+1
      const int du = (diag <= -128) ? 1 : 0;
      const int rm = lm + du;
#pragma unroll
      for (int qt = 0; qt < 2; ++qt) {
        const int rowa = (h * 2 + qt) * 16 + rm;
        const int base = (rowa == 64) ? (64 * 84 + jl0)
                                      : (rowa * 84 + 15 + jl0 - (rm & 15));
#pragma unroll
        for (int r = 0; r < 4; ++r) {
          const float pv = bf2f((unsigned short)T[base + r]);
          const float p = exp2f((cacc[qt][r] + pv) * 0.18033688f);
          lsum[qt] += p;
          pf[qt][r] = (short)f2bf(p);
        }
      }
    } else {  // boundary tiles (diag in {0,-64}): per-element delta/zero
#pragma unroll
      for (int qt = 0; qt < 2; ++qt) {
        const int qs = h * 2 + qt;
#pragma unroll
        for (int r = 0; r < 4; ++r) {
          const int jl = jl0 + r;
          const int d = (j0 - i0) + jl - (qs * 16 + lm);
          float pv;
          if (d == 1) {
            pv = 0.f;
          } else {
            const int rm2 = lm + ((d > 1) ? 1 : 0);
            const int rowa = qs * 16 + rm2;
            const int base = (rowa == 64) ? (64 * 84 + jl)
                                          : (rowa * 84 + 15 + jl - (rm2 & 15));
            pv = bf2f((unsigned short)T[base]);
          }
          const float p = exp2f((cacc[qt][r] + pv) * 0.18033688f);
          lsum[qt] += p;
          pf[qt][r] = (short)f2bf(p);
        }
      }
    }
    // (e) PV: K=16 MFMA, P in A-frag layout; V B-frags from registers.
#pragma unroll
    for (int dt = 0; dt < 4; ++dt) {
      oacc[0][dt] = __builtin_amdgcn_mfma_f32_16x16x16bf16_1k(pf[0], vf[dt], oacc[0][dt], 0, 0, 0);
      oacc[1][dt] = __builtin_amdgcn_mfma_f32_16x16x16bf16_1k(pf[1], vf[dt], oacc[1][dt], 0, 0, 0);
    }
  }
  // Epilogue: reduce k-slice partials across the 4 wk-waves of each q-half.
#pragma unroll
  for (int qt = 0; qt < 2; ++qt) {  // sum the 4 lq lanes (k within slice)
    lsum[qt] += __shfl_xor(lsum[qt], 16, 64);
    lsum[qt] += __shfl_xor(lsum[qt], 32, 64);
  }
  __syncthreads();
  if (wk == 0) {
#pragma unroll
    for (int qt = 0; qt < 2; ++qt) {
      const int qc = (h * 2 + qt) * 16;
#pragma unroll
      for (int dt = 0; dt < 4; ++dt)
        *(f32x4*)&Ored[(dt * 16 + lm) * 68 + qc + lq * 4] = oacc[qt][dt];
      if (lq == 0) Ored[64 * 68 + qc + lm] = lsum[qt];
    }
  }
  __syncthreads();
#pragma unroll 1
  for (int r = 1; r < 4; ++r) {
    if (wk == r) {
#pragma unroll
      for (int qt = 0; qt < 2; ++qt) {
        const int qc = (h * 2 + qt) * 16;
#pragma unroll
        for (int dt = 0; dt < 4; ++dt) {
          f32x4 o = *(const f32x4*)&Ored[(dt * 16 + lm) * 68 + qc + lq * 4];
          o += oacc[qt][dt];
          *(f32x4*)&Ored[(dt * 16 + lm) * 68 + qc + lq * 4] = o;
        }
        if (lq == 0) Ored[64 * 68 + qc + lm] += lsum[qt];
      }
    }
    __syncthreads();
  }
  if (w < 4) {  // waves 0..3 write q-stripes w
    const int b = bh >> 3, hh = bh & 7;
    const f32x4 lv = *(const f32x4*)&Ored[64 * 68 + w * 16 + lq * 4];
    f32x4 inv;
#pragma unroll
    for (int r = 0; r < 4; ++r) inv[r] = 1.f / lv[r];
#pragma unroll
    for (int dt = 0; dt < 4; ++dt) {
      const f32x4 o = *(const f32x4*)&Ored[(dt * 16 + lm) * 68 + w * 16 + lq * 4];
#pragma unroll
      for (int r = 0; r < 4; ++r)
        og[((size_t)b * 2048 + i0 + w * 16 + lq * 4 + r) * 512 + hh * 64 + dt * 16 + lm] =
            f2bf(o[r] * inv[r]);
    }
  }
}

// out = O @ Wproj^T + bproj, 128-tile (og/wproj bf16, bproj/out fp32)
__global__ __launch_bounds__(256) void k_gemm_proj(const unsigned short* __restrict__ og,
    const unsigned short* __restrict__ wjb, const float* __restrict__ bproj,
    float* __restrict__ out) {
  __shared__ short Asl[128 * 64], Wsl[128 * 64];
  f32x4 acc[4][4];
  const int m0 = blockIdx.y * 128, cc0 = blockIdx.x * 128;
  gemm128_mainloop(og + (size_t)m0 * 512, wjb + (size_t)cc0 * 512, Asl, Wsl, acc);
  const int tid = threadIdx.x, w = tid >> 6, lane = tid & 63, lm = lane & 15, lq = lane >> 4;
  const int wm = w >> 1, wn = w & 1;
#pragma unroll
  for (int nt = 0; nt < 4; ++nt) {
    const int cc = cc0 + wn * 64 + nt * 16 + lm;
    const float bias = bproj[cc];
#pragma unroll
    for (int mt = 0; mt < 4; ++mt) {
#pragma unroll
      for (int r = 0; r < 4; ++r) {
        const int m = m0 + wm * 64 + mt * 16 + lq * 4 + r;
        out[(size_t)m * 512 + cc] = acc[mt][nt][r] + bias;
      }
    }
  }
}

extern "C" void kernel_launch(void* const* d_in, const int* in_sizes, int n_in,
                              void* d_out, int out_size, void* d_ws, size_t ws_size,
                              hipStream_t stream) {
  const float* x     = (const float*)d_in[0];
  const float* pe    = (const float*)d_in[1];
  const float* wqkv  = (const float*)d_in[2];
  const float* wpos  = (const float*)d_in[3];
  const float* ub    = (const float*)d_in[4];
  const float* vb    = (const float*)d_in[5];
  const float* wproj = (const float*)d_in[6];
  const float* bproj = (const float*)d_in[7];
  float* out = (float*)d_out;
  unsigned short* ws = (unsigned short*)d_ws;

  const size_t SZ = (size_t)2 * 8 * 2048 * 64;  // one [B,H,N,HD] buffer (2M elems)
  unsigned short* qu   = ws;
  unsigned short* qv   = qu + SZ;
  unsigned short* kg   = qv + SZ;
  unsigned short* vt   = kg + SZ;   // [B,H,HD,N], written directly by qkvpos
  unsigned short* pos  = vt + SZ;
  unsigned short* og   = pos + SZ;
  unsigned short* cvtb = og + SZ;  // bf16: x | pe | wqkv | wpos | wproj
  unsigned short* xb   = cvtb;
  unsigned short* peb  = cvtb + 2097152;
  unsigned short* wqb  = cvtb + 4194304;
  unsigned short* wpb  = cvtb + 4980736;
  unsigned short* wjb  = cvtb + 5242880;

  dim3 blk(256);
  hipLaunchKernelGGL(k_cvt,         dim3(2688),   blk, 0, stream, x, pe, wqkv, wpos, wproj, cvtb);
  hipLaunchKernelGGL(k_gemm_qkvpos, dim3(16, 32), blk, 0, stream,
                     xb, peb, wqb, wpb, ub, vb, qu, qv, kg, vt, pos);
  hipLaunchKernelGGL(k_flash,       dim3(32, 16), dim3(512), 0, stream, qu, qv, kg, vt, pos, og);
  hipLaunchKernelGGL(k_gemm_proj,   dim3(4, 32),  blk, 0, stream, og, wjb, bproj, out);
}

// Round 9
// 213.728 us; speedup vs baseline: 1.4859x; 1.4859x over previous
//
#include <hip/hip_runtime.h>

// Problem constants: B=2, N=2048, C=512, H=8, HD=64
// Inputs fp32 (per reference); intermediates bf16 in ws; output fp32.
// R8 post-mortem: cooperative-launch fusion of k_cvt+k_gemm_qkvpos failed
// correctness (silent coop-launch failure under the harness's graph capture).
// This source is the byte-for-byte revert to the R6 configuration (213.8us,
// passed), the best verified state of the session.
typedef __attribute__((ext_vector_type(8))) short bf16x8;
typedef __attribute__((ext_vector_type(4))) short bf16x4;
typedef __attribute__((ext_vector_type(4))) float f32x4;

__device__ __forceinline__ float bf2f(unsigned short u) {
  union { unsigned int i; float f; } c; c.i = ((unsigned int)u) << 16; return c.f;
}
__device__ __forceinline__ unsigned short f2bf(float x) {
  union { float f; unsigned int i; } c; c.f = x;
  return (unsigned short)((c.i + 0x7fffu + ((c.i >> 16) & 1u)) >> 16);
}
__device__ __forceinline__ unsigned int pk2(float a, float b) {
  return (unsigned int)f2bf(a) | ((unsigned int)f2bf(b) << 16);
}

__device__ __forceinline__ uint4 ld8f(const float* p) {
  const float4 a = *(const float4*)p;
  const float4 b = *(const float4*)(p + 4);
  uint4 r;
  r.x = (unsigned)f2bf(a.x) | ((unsigned)f2bf(a.y) << 16);
  r.y = (unsigned)f2bf(a.z) | ((unsigned)f2bf(a.w) << 16);
  r.z = (unsigned)f2bf(b.x) | ((unsigned)f2bf(b.y) << 16);
  r.w = (unsigned)f2bf(b.z) | ((unsigned)f2bf(b.w) << 16);
  return r;
}

// Async global->LDS, 16B per lane: HW writes lds_base + lane*16.
__device__ __forceinline__ void gload16(const unsigned short* g, short* l) {
  __builtin_amdgcn_global_load_lds((const __attribute__((address_space(1))) void*)g,
                                   (__attribute__((address_space(3))) void*)l, 16, 0, 0);
}

// fp32 -> bf16 pre-convert of x, pe, Wqkv, Wpos, Wproj (R11-proven).
__global__ __launch_bounds__(256) void k_cvt(const float* __restrict__ x,
    const float* __restrict__ pe, const float* __restrict__ wq,
    const float* __restrict__ wp, const float* __restrict__ wj,
    unsigned short* __restrict__ dst) {
  const long long i8 = ((long long)blockIdx.x * 256 + threadIdx.x) * 8;
  const float* src; long long off;
  if (i8 < 2097152)      { src = x;  off = i8; }
  else if (i8 < 4194304) { src = pe; off = i8 - 2097152; }
  else if (i8 < 4980736) { src = wq; off = i8 - 4194304; }
  else if (i8 < 5242880) { src = wp; off = i8 - 4980736; }
  else                   { src = wj; off = i8 - 5242880; }
  *(uint4*)&dst[i8] = ld8f(src + off);
}

// 128x128 NT GEMM mainloop (m97 ladder): 256 threads = 2x2 waves, each wave a
// 64x64 subtile (4x4 MFMA 16x16x32). Staging via global_load_lds width=16.
__device__ __forceinline__ void gemm128_mainloop(const unsigned short* __restrict__ Arow,
                                                 const unsigned short* __restrict__ Wrow,
                                                 short* Asl, short* Wsl, f32x4 acc[4][4]) {
  const int tid = threadIdx.x, w = tid >> 6, lane = tid & 63, lm = lane & 15, lq = lane >> 4;
  const int wm = w >> 1, wn = w & 1;
  const int lrow = lane >> 3;                       // 0..7 within an 8-row slab
  const int gcol = (((lane & 7) ^ lrow) * 8);       // swizzled source chunk
#pragma unroll
  for (int mt = 0; mt < 4; ++mt)
#pragma unroll
    for (int nt = 0; nt < 4; ++nt) acc[mt][nt] = (f32x4){0.f, 0.f, 0.f, 0.f};
#pragma unroll 1
  for (int kc = 0; kc < 512; kc += 64) {
    __syncthreads();  // prior iteration's frag reads done
#pragma unroll
    for (int ld = 0; ld < 4; ++ld) {
      const int rbase = w * 32 + ld * 8;
      gload16(&Arow[(size_t)(rbase + lrow) * 512 + kc + gcol], &Asl[rbase * 64]);
      gload16(&Wrow[(size_t)(rbase + lrow) * 512 + kc + gcol], &Wsl[rbase * 64]);
    }
    __syncthreads();  // staging visible (vmcnt drained by barrier)
#pragma unroll
    for (int kk = 0; kk < 2; ++kk) {
      const int pcs = ((kk * 4 + lq) ^ (lm & 7)) * 8;
      bf16x8 af[4], bfr[4];
#pragma unroll
      for (int mt = 0; mt < 4; ++mt)
        af[mt] = *(const bf16x8*)&Asl[(wm * 64 + mt * 16 + lm) * 64 + pcs];
#pragma unroll
      for (int nt = 0; nt < 4; ++nt)
        bfr[nt] = *(const bf16x8*)&Wsl[(wn * 64 + nt * 16 + lm) * 64 + pcs];
#pragma unroll
      for (int mt = 0; mt < 4; ++mt)
#pragma unroll
        for (int nt = 0; nt < 4; ++nt)
          acc[mt][nt] = __builtin_amdgcn_mfma_f32_16x16x32_bf16(af[mt], bfr[nt], acc[mt][nt], 0, 0, 0);
    }
  }
}

// Coalesced epilogue via LDS transpose buffer TT[128][130] bf16 (aliases the
// GEMM staging LDS). Phase A: acc (+optional bias, fp32 add BEFORE rounding)
// -> TT[m_local][cc_local]. Phase B: uint4 rows to dst[bh][n][d].
__device__ __forceinline__ void epi_rows(const f32x4 acc[4][4], const float* __restrict__ bias,
                                         short* TT, unsigned short* __restrict__ dst,
                                         int m0, int cc0) {
  const int tid = threadIdx.x, w = tid >> 6, lane = tid & 63, lm = lane & 15, lq = lane >> 4;
  const int wm = w >> 1, wn = w & 1;
  __syncthreads();  // prior LDS use (mainloop frags / previous phase B) done
#pragma unroll
  for (int mt = 0; mt < 4; ++mt)
#pragma unroll
    for (int nt = 0; nt < 4; ++nt) {
      const int ccl = wn * 64 + nt * 16 + lm;
      const float bb = bias ? bias[(cc0 + ccl) & 511] : 0.f;
#pragma unroll
      for (int r = 0; r < 4; ++r)
        TT[(wm * 64 + mt * 16 + lq * 4 + r) * 130 + ccl] = (short)f2bf(acc[mt][nt][r] + bb);
    }
  __syncthreads();  // TT visible
#pragma unroll
  for (int rr = 0; rr < 8; ++rr) {
    const int ml = rr * 16 + (tid >> 4), ccl = (tid & 15) * 8;
    const uint4 v = *(const uint4*)&TT[ml * 130 + ccl];
    const int m = m0 + ml, b = m >> 11, n = m & 2047;
    const int cc = cc0 + ccl, hh = (cc >> 6) & 7, d = cc & 63;
    *(uint4*)&dst[((size_t)(b * 8 + hh) * 2048 + n) * 64 + d] = v;
  }
}

// Transposed epilogue for the V section: TT[m][cc] read along m, emit
// vt[bh][d][n] rows (coalesced). Fuses the old k_transpose_v kernel.
__device__ __forceinline__ void epi_cols(const f32x4 acc[4][4], short* TT,
                                         unsigned short* __restrict__ vt,
                                         int m0, int cc0) {
  const int tid = threadIdx.x, w = tid >> 6, lane = tid & 63, lm = lane & 15, lq = lane >> 4;
  const int wm = w >> 1, wn = w & 1;
  __syncthreads();
#pragma unroll
  for (int mt = 0; mt < 4; ++mt)
#pragma unroll
    for (int nt = 0; nt < 4; ++nt) {
      const int ccl = wn * 64 + nt * 16 + lm;
#pragma unroll
      for (int r = 0; r < 4; ++r)
        TT[(wm * 64 + mt * 16 + lq * 4 + r) * 130 + ccl] = (short)f2bf(acc[mt][nt][r]);
    }
  __syncthreads();
  const int b = m0 >> 11;
#pragma unroll
  for (int ss = 0; ss < 8; ++ss) {
    const int ccl = ss * 16 + (tid >> 4), mch = (tid & 15) * 8;
    alignas(16) unsigned short tmp[8];
#pragma unroll
    for (int j = 0; j < 8; ++j) tmp[j] = (unsigned short)TT[(mch + j) * 130 + ccl];
    const int cc = cc0 + ccl, hh = (cc >> 6) & 7, d = cc & 63;
    const int n = (m0 & 2047) + mch;
    *(uint4*)&vt[((size_t)(b * 8 + hh) * 64 + d) * 2048 + n] = *(const uint4*)tmp;
  }
}

// Fused 128-tile: qkv = x @ Wqkv^T (cc0 < 1536) and pos = pe @ Wpos^T.
// sec 0 -> qu/qv (two bias passes), 1 -> k, 2 -> V transposed direct to vt,
// 3 -> pos. All stores coalesced via TT.
__global__ __launch_bounds__(256) void k_gemm_qkvpos(const unsigned short* __restrict__ xb,
    const unsigned short* __restrict__ peb, const unsigned short* __restrict__ wqb,
    const unsigned short* __restrict__ wpb, const float* __restrict__ ub,
    const float* __restrict__ vb, unsigned short* __restrict__ qu,
    unsigned short* __restrict__ qv, unsigned short* __restrict__ kg,
    unsigned short* __restrict__ vt, unsigned short* __restrict__ pos) {
  __shared__ short SB[16640];  // mainloop: A[0:8192)+W[8192:16384); epi: TT[128][130]
  f32x4 acc[4][4];
  const int m0 = blockIdx.y * 128, cc0 = blockIdx.x * 128;
  const unsigned short* Arow = (cc0 < 1536 ? xb : peb) + (size_t)m0 * 512;
  const unsigned short* Wrow = (cc0 < 1536) ? (wqb + (size_t)cc0 * 512)
                                            : (wpb + (size_t)(cc0 - 1536) * 512);
  gemm128_mainloop(Arow, Wrow, SB, SB + 8192, acc);
  const int sec = cc0 >> 9;  // block-uniform (cc0 multiple of 128)
  if (sec == 0) {
    epi_rows(acc, ub, SB, qu, m0, cc0);
    epi_rows(acc, vb, SB, qv, m0, cc0);
  } else if (sec == 1) {
    epi_rows(acc, nullptr, SB, kg, m0, cc0);
  } else if (sec == 2) {
    epi_cols(acc, SB, vt, m0, cc0);
  } else {
    epi_rows(acc, nullptr, SB, pos, m0, cc0);
  }
}

// Fused flash attention v6 (R4/R6, 113.2-114.4us proven): 512 threads /
// 8 waves over 64x64 KV tiles. Waves split each tile: k-slice wk=w&3 x
// q-half h=w>>2 (cacc[2], oacc[2][4]); T-build stripe sw=w>>1, half ph=w&1
// (phases {0,1,2}/{3,4}+edge). 47.8KB LDS -> 2 blocks/CU = 16 waves/CU.
// (R5 direct-global frags: 301us, refuted. R7 reg-preload de-phasing:
// scratch-spilled 400MB -> 220us, refuted. Staged 3-barrier form is the
// proven floor for this decomposition.)
__global__ __launch_bounds__(512, 4) void k_flash(const unsigned short* __restrict__ qu,
    const unsigned short* __restrict__ qv, const unsigned short* __restrict__ kg,
    const unsigned short* __restrict__ vt, const unsigned short* __restrict__ posg,
    unsigned short* __restrict__ og) {
  // LDS (shorts): Ks[64][72] K-tile [k][d]; Vs[64][72] V-tile [d][j];
  // Pn[128][72] circular pos window; T[65][84] pos-products [q-local][c].
  __shared__ short SB[23892];
  short* Ks = SB;
  short* Vs = SB + 4608;
  short* Pn = SB + 9216;
  short* T  = SB + 18432;
  float* Ored = (float*)SB;  // epilogue alias: [65][68] f32, row 64 = lsum
  const int tid = threadIdx.x, w = tid >> 6, lane = tid & 63, lm = lane & 15, lq = lane >> 4;
  const int wk = w & 3;   // k-slice within tile
  const int h  = w >> 2;  // q-half (stripes {2h, 2h+1})
  const int sw = w >> 1;  // T-build stripe
  const int ph = w & 1;   // T-build phase-half
  // XCD-aware remap (bijective on [0,512)): hw&7 = XCD; each XCD owns bh pair
  // {2*xcd, 2*xcd+1} with all 32 i-tiles -> per-XCD working set ~2.5MB < 4MB L2.
  const int hw = blockIdx.x + 32 * blockIdx.y;
  const int xcd = hw & 7, idx = hw >> 3;
  const int bh = xcd * 2 + (idx & 1);
  const int i0 = (idx >> 1) * 64;
  const size_t bhs = (size_t)bh;
  const unsigned short* qub = qu + bhs * (2048 * 64);
  const unsigned short* qvb = qv + bhs * (2048 * 64);
  const unsigned short* pob = posg + bhs * (2048 * 64);
  // (q+u) B-frags for this wave's two q-stripes (content scores).
  bf16x8 au[2][2];
#pragma unroll
  for (int qt = 0; qt < 2; ++qt) {
    const int qs = h * 2 + qt;
    au[qt][0] = *(const bf16x8*)&qub[(size_t)(i0 + qs * 16 + lm) * 64 + lq * 8];
    au[qt][1] = *(const bf16x8*)&qub[(size_t)(i0 + qs * 16 + lm) * 64 + 32 + lq * 8];
  }
  // (q+v) frags for T-build stripe sw, and edge rows (T row 64 = q_{i0+64}).
  const bf16x8 av0 = *(const bf16x8*)&qvb[(size_t)(i0 + sw * 16 + lm) * 64 + lq * 8];
  const bf16x8 av1 = *(const bf16x8*)&qvb[(size_t)(i0 + sw * 16 + lm) * 64 + 32 + lq * 8];
  const int rowe = min(i0 + 49 + lm, 2047);  // row 64 never read when i0==1984
  const bf16x8 ae0 = *(const bf16x8*)&qvb[(size_t)rowe * 64 + lq * 8];
  const bf16x8 ae1 = *(const bf16x8*)&qvb[(size_t)rowe * 64 + 32 + lq * 8];
  float lsum[2] = {0.f, 0.f};  // q = (h*2+qt)*16+lm, own k-slice partial
  f32x4 oacc[2][4];            // [qt][dt]: q=i0+(h*2+qt)*16+lq*4+r, d=dt*16+lm
#pragma unroll
  for (int ii = 0; ii < 2; ++ii)
#pragma unroll
    for (int jj = 0; jj < 4; ++jj) oacc[ii][jj] = (f32x4){0.f, 0.f, 0.f, 0.f};
  const int krow = tid >> 3, kc8 = (tid & 7) * 8;  // 512 threads = 64 rows x 8 chunks
  const int pb0 = 1983 - i0;
  uint4 kr = *(const uint4*)&kg[(bhs * 2048 + krow) * 64 + kc8];
  uint4 vr = *(const uint4*)&vt[(bhs * 64 + krow) * 2048 + kc8];
  uint4 pr[2];
#pragma unroll
  for (int s = 0; s < 2; ++s) {
    int u = tid + s * 512, prow = u >> 3, c8 = (u & 7) * 8;
    int grow = (pb0 + prow + 4096) & 2047;
    pr[s] = *(const uint4*)&pob[(size_t)grow * 64 + c8];
  }
#pragma unroll 1
  for (int jt = 0; jt < 32; ++jt) {
    const int j0 = jt * 64;
    const int pb = pb0 + j0;
    __syncthreads();  // S1: prior iteration's LDS reads done
    *(uint4*)&Ks[krow * 72 + kc8] = kr;
    *(uint4*)&Vs[krow * 72 + kc8] = vr;
    if (jt == 0) {
#pragma unroll
      for (int s = 0; s < 2; ++s) {
        int u = tid + s * 512, prow = u >> 3, c8 = (u & 7) * 8;
        int slot = (pb + prow) & 127;
        *(uint4*)&Pn[slot * 72 + c8] = pr[s];
      }
    } else {
      const int slot = (pb + 64 + krow) & 127;
      *(uint4*)&Pn[slot * 72 + kc8] = pr[0];
    }
    __syncthreads();  // S2: staging visible
    if (jt < 31) {
      const int jn = j0 + 64;
      kr = *(const uint4*)&kg[(bhs * 2048 + jn + krow) * 64 + kc8];
      vr = *(const uint4*)&vt[(bhs * 64 + krow) * 2048 + jn + kc8];
      const int grow = (pb + 128 + krow + 4096) & 2047;
      pr[0] = *(const uint4*)&pob[(size_t)grow * 64 + kc8];
    }
    // Content scores, swapped operands: cacc[qt][r] =
    //   (q_{i0+(h*2+qt)*16+lm}+u) . K_{j0+wk*16+lq*4+r}
    const bf16x8 k0 = *(const bf16x8*)&Ks[(wk * 16 + lm) * 72 + lq * 8];
    const bf16x8 k1 = *(const bf16x8*)&Ks[(wk * 16 + lm) * 72 + 32 + lq * 8];
    f32x4 cacc[2];
#pragma unroll
    for (int qt = 0; qt < 2; ++qt) {
      cacc[qt] = __builtin_amdgcn_mfma_f32_16x16x32_bf16(k0, au[qt][0], (f32x4){0.f,0.f,0.f,0.f}, 0, 0, 0);
      cacc[qt] = __builtin_amdgcn_mfma_f32_16x16x32_bf16(k1, au[qt][1], cacc[qt], 0, 0, 0);
    }
    // T build: stripe sw rows qg=sw*16+lm over cols c=0..79, split by ph.
    // T[qg][c] = (q_{i0+qg}+v) . pos_{(pb + c + 49 - 16*sw) mod 2048}
    const int sbase = 49 - sw * 16;
    if (ph == 0) {
#pragma unroll
      for (int ct = 0; ct < 3; ++ct) {
        const int slot = (pb + sbase + ct * 16 + lm) & 127;
        const bf16x8 b0 = *(const bf16x8*)&Pn[slot * 72 + lq * 8];
        const bf16x8 b1 = *(const bf16x8*)&Pn[slot * 72 + 32 + lq * 8];
        f32x4 t0 = __builtin_amdgcn_mfma_f32_16x16x32_bf16(b0, av0, (f32x4){0.f,0.f,0.f,0.f}, 0, 0, 0);
        t0 = __builtin_amdgcn_mfma_f32_16x16x32_bf16(b1, av1, t0, 0, 0, 0);
        uint2 pk; pk.x = pk2(t0[0], t0[1]); pk.y = pk2(t0[2], t0[3]);
        *(uint2*)&T[(sw * 16 + lm) * 84 + ct * 16 + lq * 4] = pk;
      }
    } else {
#pragma unroll
      for (int ct = 3; ct < 5; ++ct) {
        const int slot = (pb + sbase + ct * 16 + lm) & 127;
        const bf16x8 b0 = *(const bf16x8*)&Pn[slot * 72 + lq * 8];
        const bf16x8 b1 = *(const bf16x8*)&Pn[slot * 72 + 32 + lq * 8];
        f32x4 t0 = __builtin_amdgcn_mfma_f32_16x16x32_bf16(b0, av0, (f32x4){0.f,0.f,0.f,0.f}, 0, 0, 0);
        t0 = __builtin_amdgcn_mfma_f32_16x16x32_bf16(b1, av1, t0, 0, 0, 0);
        uint2 pk; pk.x = pk2(t0[0], t0[1]); pk.y = pk2(t0[2], t0[3]);
        *(uint2*)&T[(sw * 16 + lm) * 84 + ct * 16 + lq * 4] = pk;
      }
      {  // edge row qg=64: T[64][c'] = (q_{i0+64}+v) . pos_{pb + c'}; ph1 waves
         // cover col groups c' = sw*16 + 0..15 (4 waves x 16 cols = 64).
        const int slot = (pb + sw * 16 + lm) & 127;
        const bf16x8 b0 = *(const bf16x8*)&Pn[slot * 72 + lq * 8];
        const bf16x8 b1 = *(const bf16x8*)&Pn[slot * 72 + 32 + lq * 8];
        f32x4 e0 = __builtin_amdgcn_mfma_f32_16x16x32_bf16(b0, ae0, (f32x4){0.f,0.f,0.f,0.f}, 0, 0, 0);
        e0 = __builtin_amdgcn_mfma_f32_16x16x32_bf16(b1, ae1, e0, 0, 0, 0);
        if (lm == 15) {
          uint2 pk; pk.x = pk2(e0[0], e0[1]); pk.y = pk2(e0[2], e0[3]);
          *(uint2*)&T[64 * 84 + sw * 16 + lq * 4] = pk;
        }
      }
    }
    __syncthreads();  // S3: T visible cross-wave
    // Gather pos addend + softmax-exp + in-lane bf16 pack (PV A-frags).
    const int diag = i0 - j0;
    const int jl0 = wk * 16 + lq * 4;
    bf16x4 pf[2];
    if (diag >= 64 || diag <= -128) {  // fast: delta uniform, no j==i+1
      const int du = (diag <= -128) ? 1 : 0;
      const int rm = lm + du;
#pragma unroll
      for (int qt = 0; qt < 2; ++qt) {
        const int rowa = (h * 2 + qt) * 16 + rm;
        const int base = (rowa == 64) ? (64 * 84 + jl0)
                                      : (rowa * 84 + 15 + jl0 - (rm & 15));
#pragma unroll
        for (int r = 0; r < 4; ++r) {
          const float pv = bf2f((unsigned short)T[base + r]);
          const float p = exp2f((cacc[qt][r] + pv) * 0.18033688f);
          lsum[qt] += p;
          pf[qt][r] = (short)f2bf(p);
        }
      }
    } else {  // boundary tiles (diag in {0,-64}): per-element delta/zero
#pragma unroll
      for (int qt = 0; qt < 2; ++qt) {
        const int qs = h * 2 + qt;
#pragma unroll
        for (int r = 0; r < 4; ++r) {
          const int jl = jl0 + r;
          const int d = (j0 - i0) + jl - (qs * 16 + lm);
          float pv;
          if (d == 1) {
            pv = 0.f;
          } else {
            const int rm2 = lm + ((d > 1) ? 1 : 0);
            const int rowa = qs * 16 + rm2;
            const int base = (rowa == 64) ? (64 * 84 + jl)
                                          : (rowa * 84 + 15 + jl - (rm2 & 15));
            pv = bf2f((unsigned short)T[base]);
          }
          const float p = exp2f((cacc[qt][r] + pv) * 0.18033688f);
          lsum[qt] += p;
          pf[qt][r] = (short)f2bf(p);
        }
      }
    }
    // PV: K=16 MFMA, P already in A-frag layout; V B-frag = wave's k-slice.
#pragma unroll
    for (int dt = 0; dt < 4; ++dt) {
      const bf16x4 vf = *(const bf16x4*)&Vs[(dt * 16 + lm) * 72 + wk * 16 + lq * 4];
      oacc[0][dt] = __builtin_amdgcn_mfma_f32_16x16x16bf16_1k(pf[0], vf, oacc[0][dt], 0, 0, 0);
      oacc[1][dt] = __builtin_amdgcn_mfma_f32_16x16x16bf16_1k(pf[1], vf, oacc[1][dt], 0, 0, 0);
    }
  }
  // Epilogue: reduce k-slice partials across the 4 wk-waves of each q-half.
#pragma unroll
  for (int qt = 0; qt < 2; ++qt) {  // sum the 4 lq lanes (k within slice)
    lsum[qt] += __shfl_xor(lsum[qt], 16, 64);
    lsum[qt] += __shfl_xor(lsum[qt], 32, 64);
  }
  __syncthreads();
  if (wk == 0) {
#pragma unroll
    for (int qt = 0; qt < 2; ++qt) {
      const int qc = (h * 2 + qt) * 16;
#pragma unroll
      for (int dt = 0; dt < 4; ++dt)
        *(f32x4*)&Ored[(dt * 16 + lm) * 68 + qc + lq * 4] = oacc[qt][dt];
      if (lq == 0) Ored[64 * 68 + qc + lm] = lsum[qt];
    }
  }
  __syncthreads();
#pragma unroll 1
  for (int r = 1; r < 4; ++r) {
    if (wk == r) {
#pragma unroll
      for (int qt = 0; qt < 2; ++qt) {
        const int qc = (h * 2 + qt) * 16;
#pragma unroll
        for (int dt = 0; dt < 4; ++dt) {
          f32x4 o = *(const f32x4*)&Ored[(dt * 16 + lm) * 68 + qc + lq * 4];
          o += oacc[qt][dt];
          *(f32x4*)&Ored[(dt * 16 + lm) * 68 + qc + lq * 4] = o;
        }
        if (lq == 0) Ored[64 * 68 + qc + lm] += lsum[qt];
      }
    }
    __syncthreads();
  }
  if (w < 4) {  // waves 0..3 write q-stripes w
    const int b = bh >> 3, hh = bh & 7;
    const f32x4 lv = *(const f32x4*)&Ored[64 * 68 + w * 16 + lq * 4];
    f32x4 inv;
#pragma unroll
    for (int r = 0; r < 4; ++r) inv[r] = 1.f / lv[r];
#pragma unroll
    for (int dt = 0; dt < 4; ++dt) {
      const f32x4 o = *(const f32x4*)&Ored[(dt * 16 + lm) * 68 + w * 16 + lq * 4];
#pragma unroll
      for (int r = 0; r < 4; ++r)
        og[((size_t)b * 2048 + i0 + w * 16 + lq * 4 + r) * 512 + hh * 64 + dt * 16 + lm] =
            f2bf(o[r] * inv[r]);
    }
  }
}

// out = O @ Wproj^T + bproj, 128-tile (og/wproj bf16, bproj/out fp32)
__global__ __launch_bounds__(256) void k_gemm_proj(const unsigned short* __restrict__ og,
    const unsigned short* __restrict__ wjb, const float* __restrict__ bproj,
    float* __restrict__ out) {
  __shared__ short Asl[128 * 64], Wsl[128 * 64];
  f32x4 acc[4][4];
  const int m0 = blockIdx.y * 128, cc0 = blockIdx.x * 128;
  gemm128_mainloop(og + (size_t)m0 * 512, wjb + (size_t)cc0 * 512, Asl, Wsl, acc);
  const int tid = threadIdx.x, w = tid >> 6, lane = tid & 63, lm = lane & 15, lq = lane >> 4;
  const int wm = w >> 1, wn = w & 1;
#pragma unroll
  for (int nt = 0; nt < 4; ++nt) {
    const int cc = cc0 + wn * 64 + nt * 16 + lm;
    const float bias = bproj[cc];
#pragma unroll
    for (int mt = 0; mt < 4; ++mt) {
#pragma unroll
      for (int r = 0; r < 4; ++r) {
        const int m = m0 + wm * 64 + mt * 16 + lq * 4 + r;
        out[(size_t)m * 512 + cc] = acc[mt][nt][r] + bias;
      }
    }
  }
}

extern "C" void kernel_launch(void* const* d_in, const int* in_sizes, int n_in,
                              void* d_out, int out_size, void* d_ws, size_t ws_size,
                              hipStream_t stream) {
  const float* x     = (const float*)d_in[0];
  const float* pe    = (const float*)d_in[1];
  const float* wqkv  = (const float*)d_in[2];
  const float* wpos  = (const float*)d_in[3];
  const float* ub    = (const float*)d_in[4];
  const float* vb    = (const float*)d_in[5];
  const float* wproj = (const float*)d_in[6];
  const float* bproj = (const float*)d_in[7];
  float* out = (float*)d_out;
  unsigned short* ws = (unsigned short*)d_ws;

  const size_t SZ = (size_t)2 * 8 * 2048 * 64;  // one [B,H,N,HD] buffer (2M elems)
  unsigned short* qu   = ws;
  unsigned short* qv   = qu + SZ;
  unsigned short* kg   = qv + SZ;
  unsigned short* vt   = kg + SZ;   // [B,H,HD,N], written directly by qkvpos
  unsigned short* pos  = vt + SZ;
  unsigned short* og   = pos + SZ;
  unsigned short* cvtb = og + SZ;  // bf16: x | pe | wqkv | wpos | wproj
  unsigned short* xb   = cvtb;
  unsigned short* peb  = cvtb + 2097152;
  unsigned short* wqb  = cvtb + 4194304;
  unsigned short* wpb  = cvtb + 4980736;
  unsigned short* wjb  = cvtb + 5242880;

  dim3 blk(256);
  hipLaunchKernelGGL(k_cvt,         dim3(2688),   blk, 0, stream, x, pe, wqkv, wpos, wproj, cvtb);
  hipLaunchKernelGGL(k_gemm_qkvpos, dim3(16, 32), blk, 0, stream,
                     xb, peb, wqb, wpb, ub, vb, qu, qv, kg, vt, pos);
  hipLaunchKernelGGL(k_flash,       dim3(32, 16), dim3(512), 0, stream, qu, qv, kg, vt, pos, og);
  hipLaunchKernelGGL(k_gemm_proj,   dim3(4, 32),  blk, 0, stream, og, wjb, bproj, out);
}

// Round 10
// 199.911 us; speedup vs baseline: 1.5886x; 1.0691x over previous
//
#include <hip/hip_runtime.h>

// Problem constants: B=2, N=2048, C=512, H=8, HD=64
// Inputs fp32 (per reference); intermediates bf16 in ws; output fp32.
typedef __attribute__((ext_vector_type(8))) short bf16x8;
typedef __attribute__((ext_vector_type(4))) short bf16x4;
typedef __attribute__((ext_vector_type(4))) float f32x4;

__device__ __forceinline__ float bf2f(unsigned short u) {
  union { unsigned int i; float f; } c; c.i = ((unsigned int)u) << 16; return c.f;
}
__device__ __forceinline__ unsigned short f2bf(float x) {
  union { float f; unsigned int i; } c; c.f = x;
  return (unsigned short)((c.i + 0x7fffu + ((c.i >> 16) & 1u)) >> 16);
}
__device__ __forceinline__ unsigned int pk2(float a, float b) {
  return (unsigned int)f2bf(a) | ((unsigned int)f2bf(b) << 16);
}

__device__ __forceinline__ uint4 ld8f(const float* p) {
  const float4 a = *(const float4*)p;
  const float4 b = *(const float4*)(p + 4);
  uint4 r;
  r.x = (unsigned)f2bf(a.x) | ((unsigned)f2bf(a.y) << 16);
  r.y = (unsigned)f2bf(a.z) | ((unsigned)f2bf(a.w) << 16);
  r.z = (unsigned)f2bf(b.x) | ((unsigned)f2bf(b.y) << 16);
  r.w = (unsigned)f2bf(b.z) | ((unsigned)f2bf(b.w) << 16);
  return r;
}

// Async global->LDS, 16B per lane: HW writes lds_base + lane*16.
__device__ __forceinline__ void gload16(const unsigned short* g, short* l) {
  __builtin_amdgcn_global_load_lds((const __attribute__((address_space(1))) void*)g,
                                   (__attribute__((address_space(3))) void*)l, 16, 0, 0);
}

// fp32 -> bf16 pre-convert of x, pe, Wqkv, Wpos, Wproj (R11-proven).
__global__ __launch_bounds__(256) void k_cvt(const float* __restrict__ x,
    const float* __restrict__ pe, const float* __restrict__ wq,
    const float* __restrict__ wp, const float* __restrict__ wj,
    unsigned short* __restrict__ dst) {
  const long long i8 = ((long long)blockIdx.x * 256 + threadIdx.x) * 8;
  const float* src; long long off;
  if (i8 < 2097152)      { src = x;  off = i8; }
  else if (i8 < 4194304) { src = pe; off = i8 - 2097152; }
  else if (i8 < 4980736) { src = wq; off = i8 - 4194304; }
  else if (i8 < 5242880) { src = wp; off = i8 - 4980736; }
  else                   { src = wj; off = i8 - 5242880; }
  *(uint4*)&dst[i8] = ld8f(src + off);
}

// 128x128 NT GEMM mainloop (m97 ladder): 256 threads = 2x2 waves, each wave a
// 64x64 subtile (4x4 MFMA 16x16x32). Staging via global_load_lds width=16.
__device__ __forceinline__ void gemm128_mainloop(const unsigned short* __restrict__ Arow,
                                                 const unsigned short* __restrict__ Wrow,
                                                 short* Asl, short* Wsl, f32x4 acc[4][4]) {
  const int tid = threadIdx.x, w = tid >> 6, lane = tid & 63, lm = lane & 15, lq = lane >> 4;
  const int wm = w >> 1, wn = w & 1;
  const int lrow = lane >> 3;                       // 0..7 within an 8-row slab
  const int gcol = (((lane & 7) ^ lrow) * 8);       // swizzled source chunk
#pragma unroll
  for (int mt = 0; mt < 4; ++mt)
#pragma unroll
    for (int nt = 0; nt < 4; ++nt) acc[mt][nt] = (f32x4){0.f, 0.f, 0.f, 0.f};
#pragma unroll 1
  for (int kc = 0; kc < 512; kc += 64) {
    __syncthreads();  // prior iteration's frag reads done
#pragma unroll
    for (int ld = 0; ld < 4; ++ld) {
      const int rbase = w * 32 + ld * 8;
      gload16(&Arow[(size_t)(rbase + lrow) * 512 + kc + gcol], &Asl[rbase * 64]);
      gload16(&Wrow[(size_t)(rbase + lrow) * 512 + kc + gcol], &Wsl[rbase * 64]);
    }
    __syncthreads();  // staging visible (vmcnt drained by barrier)
#pragma unroll
    for (int kk = 0; kk < 2; ++kk) {
      const int pcs = ((kk * 4 + lq) ^ (lm & 7)) * 8;
      bf16x8 af[4], bfr[4];
#pragma unroll
      for (int mt = 0; mt < 4; ++mt)
        af[mt] = *(const bf16x8*)&Asl[(wm * 64 + mt * 16 + lm) * 64 + pcs];
#pragma unroll
      for (int nt = 0; nt < 4; ++nt)
        bfr[nt] = *(const bf16x8*)&Wsl[(wn * 64 + nt * 16 + lm) * 64 + pcs];
#pragma unroll
      for (int mt = 0; mt < 4; ++mt)
#pragma unroll
        for (int nt = 0; nt < 4; ++nt)
          acc[mt][nt] = __builtin_amdgcn_mfma_f32_16x16x32_bf16(af[mt], bfr[nt], acc[mt][nt], 0, 0, 0);
    }
  }
}

// Coalesced epilogue via LDS transpose buffer TT[128][130] bf16 (aliases the
// GEMM staging LDS). Phase A: acc (+optional bias, fp32 add BEFORE rounding)
// -> TT[m_local][cc_local]. Phase B: uint4 rows to dst[bh][n][d].
__device__ __forceinline__ void epi_rows(const f32x4 acc[4][4], const float* __restrict__ bias,
                                         short* TT, unsigned short* __restrict__ dst,
                                         int m0, int cc0) {
  const int tid = threadIdx.x, w = tid >> 6, lane = tid & 63, lm = lane & 15, lq = lane >> 4;
  const int wm = w >> 1, wn = w & 1;
  __syncthreads();  // prior LDS use (mainloop frags / previous phase B) done
#pragma unroll
  for (int mt = 0; mt < 4; ++mt)
#pragma unroll
    for (int nt = 0; nt < 4; ++nt) {
      const int ccl = wn * 64 + nt * 16 + lm;
      const float bb = bias ? bias[(cc0 + ccl) & 511] : 0.f;
#pragma unroll
      for (int r = 0; r < 4; ++r)
        TT[(wm * 64 + mt * 16 + lq * 4 + r) * 130 + ccl] = (short)f2bf(acc[mt][nt][r] + bb);
    }
  __syncthreads();  // TT visible
#pragma unroll
  for (int rr = 0; rr < 8; ++rr) {
    const int ml = rr * 16 + (tid >> 4), ccl = (tid & 15) * 8;
    const uint4 v = *(const uint4*)&TT[ml * 130 + ccl];
    const int m = m0 + ml, b = m >> 11, n = m & 2047;
    const int cc = cc0 + ccl, hh = (cc >> 6) & 7, d = cc & 63;
    *(uint4*)&dst[((size_t)(b * 8 + hh) * 2048 + n) * 64 + d] = v;
  }
}

// Transposed epilogue for the V section: TT[m][cc] read along m, emit
// vt[bh][d][n] rows (coalesced). Fuses the old k_transpose_v kernel.
__device__ __forceinline__ void epi_cols(const f32x4 acc[4][4], short* TT,
                                         unsigned short* __restrict__ vt,
                                         int m0, int cc0) {
  const int tid = threadIdx.x, w = tid >> 6, lane = tid & 63, lm = lane & 15, lq = lane >> 4;
  const int wm = w >> 1, wn = w & 1;
  __syncthreads();
#pragma unroll
  for (int mt = 0; mt < 4; ++mt)
#pragma unroll
    for (int nt = 0; nt < 4; ++nt) {
      const int ccl = wn * 64 + nt * 16 + lm;
#pragma unroll
      for (int r = 0; r < 4; ++r)
        TT[(wm * 64 + mt * 16 + lq * 4 + r) * 130 + ccl] = (short)f2bf(acc[mt][nt][r]);
    }
  __syncthreads();
  const int b = m0 >> 11;
#pragma unroll
  for (int ss = 0; ss < 8; ++ss) {
    const int ccl = ss * 16 + (tid >> 4), mch = (tid & 15) * 8;
    alignas(16) unsigned short tmp[8];
#pragma unroll
    for (int j = 0; j < 8; ++j) tmp[j] = (unsigned short)TT[(mch + j) * 130 + ccl];
    const int cc = cc0 + ccl, hh = (cc >> 6) & 7, d = cc & 63;
    const int n = (m0 & 2047) + mch;
    *(uint4*)&vt[((size_t)(b * 8 + hh) * 64 + d) * 2048 + n] = *(const uint4*)tmp;
  }
}

// Fused 128-tile: qkv = x @ Wqkv^T (cc0 < 1536) and pos = pe @ Wpos^T.
__global__ __launch_bounds__(256) void k_gemm_qkvpos(const unsigned short* __restrict__ xb,
    const unsigned short* __restrict__ peb, const unsigned short* __restrict__ wqb,
    const unsigned short* __restrict__ wpb, const float* __restrict__ ub,
    const float* __restrict__ vb, unsigned short* __restrict__ qu,
    unsigned short* __restrict__ qv, unsigned short* __restrict__ kg,
    unsigned short* __restrict__ vt, unsigned short* __restrict__ pos) {
  __shared__ short SB[16640];  // mainloop: A[0:8192)+W[8192:16384); epi: TT[128][130]
  f32x4 acc[4][4];
  const int m0 = blockIdx.y * 128, cc0 = blockIdx.x * 128;
  const unsigned short* Arow = (cc0 < 1536 ? xb : peb) + (size_t)m0 * 512;
  const unsigned short* Wrow = (cc0 < 1536) ? (wqb + (size_t)cc0 * 512)
                                            : (wpb + (size_t)(cc0 - 1536) * 512);
  gemm128_mainloop(Arow, Wrow, SB, SB + 8192, acc);
  const int sec = cc0 >> 9;  // block-uniform (cc0 multiple of 128)
  if (sec == 0) {
    epi_rows(acc, ub, SB, qu, m0, cc0);
    epi_rows(acc, vb, SB, qv, m0, cc0);
  } else if (sec == 1) {
    epi_rows(acc, nullptr, SB, kg, m0, cc0);
  } else if (sec == 2) {
    epi_cols(acc, SB, vt, m0, cc0);
  } else {
    epi_rows(acc, nullptr, SB, pos, m0, cc0);
  }
}

// Fused flash attention v9 — v6's proven tile/wave decomposition, re-plumbed
// with ASYNC staging (global_load_lds) + unpadded XOR-swizzled LDS:
//  * Ks/Vs double-buffered [2][64][64], Pn[128][64] circular, stride 64 (no
//    pad). Staging = 3 gload16/thread/tile (DMA); the 3 ds_writes + prefetch
//    registers of v6 are GONE. Swizzle = gemm128's proven pattern: source
//    chunk (lane&7)^lrow on write, phys chunk = logical ^ (row&7) on read
//    (bank-verified conflict-free for K/Pn/V frag reads).
//  * 2 barriers/tile (was 3): B1 (drains DMAs; PV done) -> issue K/V(jt+1)
//    into buf^1 -> QK^T + T-build -> B2 (T visible; Pn reads done) -> issue
//    Pn(jt+1) -> gather/exp/PV. Full-tile latency cover for K/V, half-tile
//    for Pn.
//  * Pn slabs are 8-row aligned (pb === 7 mod 8 -> pb+65 aligned); per tile
//    stage offsets 65..128, prologue 1..128. Lifetime analysis: every main/
//    edge read lands before its slot's clobber EXCEPT the edge row's col 0
//    (pos_{pb}) -> carried in regs eb0/eb1 (4 lanes of wave 1), reloaded each
//    tile from Pn offset 64 before the clobber, prologue-initialized from
//    global. Offset-128 slot now holds correct data (v6's benign alias gone).
__global__ __launch_bounds__(512, 4) void k_flash(const unsigned short* __restrict__ qu,
    const unsigned short* __restrict__ qv, const unsigned short* __restrict__ kg,
    const unsigned short* __restrict__ vt, const unsigned short* __restrict__ posg,
    unsigned short* __restrict__ og) {
  // LDS (shorts): Ks[2][64][64] @0; Vs[2][64][64] @8192; Pn[128][64] @16384;
  // T[65][84] @24576. 30036 shorts = 60072 B -> 2 blocks/CU.
  __shared__ short SB[30036];
  short* KsB = SB;
  short* VsB = SB + 8192;
  short* Pn  = SB + 16384;
  short* T   = SB + 24576;
  float* Ored = (float*)SB;  // epilogue alias: [65][68] f32, row 64 = lsum
  const int tid = threadIdx.x, w = tid >> 6, lane = tid & 63, lm = lane & 15, lq = lane >> 4;
  const int wk = w & 3;   // k-slice within tile
  const int h  = w >> 2;  // q-half (stripes {2h, 2h+1})
  const int sw = w >> 1;  // T-build stripe
  const int ph = w & 1;   // T-build phase-half
  // XCD-aware remap: each XCD owns bh pair {2*xcd, 2*xcd+1}, all 32 i-tiles.
  const int hw = blockIdx.x + 32 * blockIdx.y;
  const int xcd = hw & 7, idx = hw >> 3;
  const int bh = xcd * 2 + (idx & 1);
  const int i0 = (idx >> 1) * 64;
  const size_t bhs = (size_t)bh;
  const unsigned short* qub = qu + bhs * (2048 * 64);
  const unsigned short* qvb = qv + bhs * (2048 * 64);
  const unsigned short* pob = posg + bhs * (2048 * 64);
  // Swizzled-read constants (phys chunk = logical chunk ^ (row&7)):
  const int x7 = lm & 7;
  const int kc0 = (lq ^ x7) * 8, kc1 = ((lq + 4) ^ x7) * 8;          // K & main-Pn (row&7==lm&7)
  const int xe = (lm + 7) & 7;
  const int ec0 = (lq ^ xe) * 8, ec1 = ((lq + 4) ^ xe) * 8;          // edge-Pn (slot&7==(lm-1)&7)
  const int ve = (((2 * wk + (lq >> 1)) ^ x7) * 8) + (lq & 1) * 4;   // V frag b64
  const int r0c0 = (lq ^ 7) * 8, r0c1 = ((lq + 4) ^ 7) * 8;          // eb reload (slot&7==7)
  // Staging constants (gemm128's source-swizzle pattern):
  const int lrow = lane >> 3;
  const int gcol = ((lane & 7) ^ lrow) * 8;
  const unsigned short* ksrc = &kg[(bhs * 2048 + 8 * w + lrow) * 64 + gcol];
  const unsigned short* vsrc = &vt[(bhs * 64 + 8 * w + lrow) * 2048 + gcol];
  // (q+u) B-frags for this wave's two q-stripes (content scores).
  bf16x8 au[2][2];
#pragma unroll
  for (int qt = 0; qt < 2; ++qt) {
    const int qs = h * 2 + qt;
    au[qt][0] = *(const bf16x8*)&qub[(size_t)(i0 + qs * 16 + lm) * 64 + lq * 8];
    au[qt][1] = *(const bf16x8*)&qub[(size_t)(i0 + qs * 16 + lm) * 64 + 32 + lq * 8];
  }
  // (q+v) frags for T-build stripe sw, and edge rows (T row 64 = q_{i0+64}).
  const bf16x8 av0 = *(const bf16x8*)&qvb[(size_t)(i0 + sw * 16 + lm) * 64 + lq * 8];
  const bf16x8 av1 = *(const bf16x8*)&qvb[(size_t)(i0 + sw * 16 + lm) * 64 + 32 + lq * 8];
  const int rowe = min(i0 + 49 + lm, 2047);  // row 64 never read when i0==1984
  const bf16x8 ae0 = *(const bf16x8*)&qvb[(size_t)rowe * 64 + lq * 8];
  const bf16x8 ae1 = *(const bf16x8*)&qvb[(size_t)rowe * 64 + 32 + lq * 8];
  float lsum[2] = {0.f, 0.f};  // q = (h*2+qt)*16+lm, own k-slice partial
  f32x4 oacc[2][4];            // [qt][dt]: q=i0+(h*2+qt)*16+lq*4+r, d=dt*16+lm
#pragma unroll
  for (int ii = 0; ii < 2; ++ii)
#pragma unroll
    for (int jj = 0; jj < 4; ++jj) oacc[ii][jj] = (f32x4){0.f, 0.f, 0.f, 0.f};
  const int pb0 = 1983 - i0;  // === 7 mod 8 for all blocks (incl. i0=1984 -> -1)
  // Prologue: tile-0 K/V into buf0; Pn offsets 1..128 (16 aligned slabs,
  // 2/wave); eb (pos_{pb0}) direct from global for the edge col-0 lanes.
  gload16(ksrc, &KsB[w * 512]);
  gload16(vsrc, &VsB[w * 512]);
#pragma unroll
  for (int s = 0; s < 2; ++s) {
    const int u = 2 * w + s;
    const int slotb = (pb0 + 1 + 8 * u) & 127;
    const int grow = (pb0 + 1 + 8 * u + lrow + 4096) & 2047;
    gload16(&pob[(size_t)grow * 64 + gcol], &Pn[slotb * 64]);
  }
  bf16x8 eb0 = {}, eb1 = {};
  if (w == 1 && lm == 0) {
    const int g0 = (pb0 + 4096) & 2047;
    eb0 = *(const bf16x8*)&pob[(size_t)g0 * 64 + lq * 8];
    eb1 = *(const bf16x8*)&pob[(size_t)g0 * 64 + 32 + lq * 8];
  }
#pragma unroll 1
  for (int jt = 0; jt < 32; ++jt) {
    const int j0 = jt * 64;
    const int pb = pb0 + j0;
    const int nb = jt & 1;
    short* Ks = KsB + nb * 4096;
    short* Vs = VsB + nb * 4096;
    __syncthreads();  // B1: staging(jt) drained+visible; prior tile's PV reads done
    if (jt < 31) {    // async K/V staging for jt+1 into the other buffer
      const int jn = j0 + 64;
      gload16(ksrc + (size_t)jn * 64, &KsB[(nb ^ 1) * 4096 + w * 512]);
      gload16(vsrc + jn, &VsB[(nb ^ 1) * 4096 + w * 512]);
    }
    // Content scores, swapped operands: cacc[qt][r] =
    //   (q_{i0+(h*2+qt)*16+lm}+u) . K_{j0+wk*16+lq*4+r}
    const bf16x8 k0 = *(const bf16x8*)&Ks[(wk * 16 + lm) * 64 + kc0];
    const bf16x8 k1 = *(const bf16x8*)&Ks[(wk * 16 + lm) * 64 + kc1];
    f32x4 cacc[2];
#pragma unroll
    for (int qt = 0; qt < 2; ++qt) {
      cacc[qt] = __builtin_amdgcn_mfma_f32_16x16x32_bf16(k0, au[qt][0], (f32x4){0.f,0.f,0.f,0.f}, 0, 0, 0);
      cacc[qt] = __builtin_amdgcn_mfma_f32_16x16x32_bf16(k1, au[qt][1], cacc[qt], 0, 0, 0);
    }
    // T build: stripe sw rows qg=sw*16+lm over cols c=0..79, split by ph.
    // T[qg][c] = (q_{i0+qg}+v) . pos_{(pb + c + 49 - 16*sw) mod 2048}
    const int sbase = 49 - sw * 16;
    if (ph == 0) {
#pragma unroll
      for (int ct = 0; ct < 3; ++ct) {
        const int slot = (pb + sbase + ct * 16 + lm) & 127;
        const bf16x8 b0 = *(const bf16x8*)&Pn[slot * 64 + kc0];
        const bf16x8 b1 = *(const bf16x8*)&Pn[slot * 64 + kc1];
        f32x4 t0 = __builtin_amdgcn_mfma_f32_16x16x32_bf16(b0, av0, (f32x4){0.f,0.f,0.f,0.f}, 0, 0, 0);
        t0 = __builtin_amdgcn_mfma_f32_16x16x32_bf16(b1, av1, t0, 0, 0, 0);
        uint2 pk; pk.x = pk2(t0[0], t0[1]); pk.y = pk2(t0[2], t0[3]);
        *(uint2*)&T[(sw * 16 + lm) * 84 + ct * 16 + lq * 4] = pk;
      }
    } else {
#pragma unroll
      for (int ct = 3; ct < 5; ++ct) {
        const int slot = (pb + sbase + ct * 16 + lm) & 127;
        const bf16x8 b0 = *(const bf16x8*)&Pn[slot * 64 + kc0];
        const bf16x8 b1 = *(const bf16x8*)&Pn[slot * 64 + kc1];
        f32x4 t0 = __builtin_amdgcn_mfma_f32_16x16x32_bf16(b0, av0, (f32x4){0.f,0.f,0.f,0.f}, 0, 0, 0);
        t0 = __builtin_amdgcn_mfma_f32_16x16x32_bf16(b1, av1, t0, 0, 0, 0);
        uint2 pk; pk.x = pk2(t0[0], t0[1]); pk.y = pk2(t0[2], t0[3]);
        *(uint2*)&T[(sw * 16 + lm) * 84 + ct * 16 + lq * 4] = pk;
      }
      {  // edge row qg=64: T[64][c'] = (q_{i0+64}+v) . pos_{pb + c'};
         // ph1 waves cover col groups c' = sw*16 + 0..15. Col 0's pos row
         // (offset 0) comes from regs (its Pn slot was clobbered last tile).
        bf16x8 b0, b1;
        if (sw == 0 && lm == 0) {
          b0 = eb0; b1 = eb1;
        } else {
          const int slot = (pb + sw * 16 + lm) & 127;
          b0 = *(const bf16x8*)&Pn[slot * 64 + ec0];
          b1 = *(const bf16x8*)&Pn[slot * 64 + ec1];
        }
        f32x4 e0 = __builtin_amdgcn_mfma_f32_16x16x32_bf16(b0, ae0, (f32x4){0.f,0.f,0.f,0.f}, 0, 0, 0);
        e0 = __builtin_amdgcn_mfma_f32_16x16x32_bf16(b1, ae1, e0, 0, 0, 0);
        if (lm == 15) {
          uint2 pk; pk.x = pk2(e0[0], e0[1]); pk.y = pk2(e0[2], e0[3]);
          *(uint2*)&T[64 * 84 + sw * 16 + lq * 4] = pk;
        }
        if (sw == 0 && lm == 0) {  // reload eb = pos_{pb+64} before B2's clobber
          const int sl = (pb + 64) & 127;
          eb0 = *(const bf16x8*)&Pn[sl * 64 + r0c0];
          eb1 = *(const bf16x8*)&Pn[sl * 64 + r0c1];
        }
      }
    }
    __syncthreads();  // B2: T visible cross-wave; all Pn reads of this tile done
    if (jt < 31) {    // async Pn staging: rows pb+129..pb+192 (8 aligned slabs)
      const int slotb = (pb + 129 + 8 * w) & 127;
      const int grow = (pb + 129 + 8 * w + lrow + 4096) & 2047;
      gload16(&pob[(size_t)grow * 64 + gcol], &Pn[slotb * 64]);
    }
    // Gather pos addend + softmax-exp + in-lane bf16 pack (PV A-frags).
    const int diag = i0 - j0;
    const int jl0 = wk * 16 + lq * 4;
    bf16x4 pf[2];
    if (diag >= 64 || diag <= -128) {  // fast: delta uniform, no j==i+1
      const int du = (diag <= -128) ? 1 : 0;
      const int rm = lm + du;
#pragma unroll
      for (int qt = 0; qt < 2; ++qt) {
        const int rowa = (h * 2 + qt) * 16 + rm;
        const int base = (rowa == 64) ? (64 * 84 + jl0)
                                      : (rowa * 84 + 15 + jl0 - (rm & 15));
#pragma unroll
        for (int r = 0; r < 4; ++r) {
          const float pv = bf2f((unsigned short)T[base + r]);
          const float p = exp2f((cacc[qt][r] + pv) * 0.18033688f);
          lsum[qt] += p;
          pf[qt][r] = (short)f2bf(p);
        }
      }
    } else {  // boundary tiles (diag in {0,-64}): per-element delta/zero
#pragma unroll
      for (int qt = 0; qt < 2; ++qt) {
        const int qs = h * 2 + qt;
#pragma unroll
        for (int r = 0; r < 4; ++r) {
          const int jl = jl0 + r;
          const int d = (j0 - i0) + jl - (qs * 16 + lm);
          float pv;
          if (d == 1) {
            pv = 0.f;
          } else {
            const int rm2 = lm + ((d > 1) ? 1 : 0);
            const int rowa = qs * 16 + rm2;
            const int base = (rowa == 64) ? (64 * 84 + jl)
                                          : (rowa * 84 + 15 + jl - (rm2 & 15));
            pv = bf2f((unsigned short)T[base]);
          }
          const float p = exp2f((cacc[qt][r] + pv) * 0.18033688f);
          lsum[qt] += p;
          pf[qt][r] = (short)f2bf(p);
        }
      }
    }
    // PV: K=16 MFMA, P in A-frag layout; V B-frag = wave's k-slice (swizzled).
#pragma unroll
    for (int dt = 0; dt < 4; ++dt) {
      const bf16x4 vf = *(const bf16x4*)&Vs[(dt * 16 + lm) * 64 + ve];
      oacc[0][dt] = __builtin_amdgcn_mfma_f32_16x16x16bf16_1k(pf[0], vf, oacc[0][dt], 0, 0, 0);
      oacc[1][dt] = __builtin_amdgcn_mfma_f32_16x16x16bf16_1k(pf[1], vf, oacc[1][dt], 0, 0, 0);
    }
  }
  // Epilogue: reduce k-slice partials across the 4 wk-waves of each q-half.
#pragma unroll
  for (int qt = 0; qt < 2; ++qt) {  // sum the 4 lq lanes (k within slice)
    lsum[qt] += __shfl_xor(lsum[qt], 16, 64);
    lsum[qt] += __shfl_xor(lsum[qt], 32, 64);
  }
  __syncthreads();  // PV done; stray DMAs drained; Ored alias safe
  if (wk == 0) {
#pragma unroll
    for (int qt = 0; qt < 2; ++qt) {
      const int qc = (h * 2 + qt) * 16;
#pragma unroll
      for (int dt = 0; dt < 4; ++dt)
        *(f32x4*)&Ored[(dt * 16 + lm) * 68 + qc + lq * 4] = oacc[qt][dt];
      if (lq == 0) Ored[64 * 68 + qc + lm] = lsum[qt];
    }
  }
  __syncthreads();
#pragma unroll 1
  for (int r = 1; r < 4; ++r) {
    if (wk == r) {
#pragma unroll
      for (int qt = 0; qt < 2; ++qt) {
        const int qc = (h * 2 + qt) * 16;
#pragma unroll
        for (int dt = 0; dt < 4; ++dt) {
          f32x4 o = *(const f32x4*)&Ored[(dt * 16 + lm) * 68 + qc + lq * 4];
          o += oacc[qt][dt];
          *(f32x4*)&Ored[(dt * 16 + lm) * 68 + qc + lq * 4] = o;
        }
        if (lq == 0) Ored[64 * 68 + qc + lm] += lsum[qt];
      }
    }
    __syncthreads();
  }
  if (w < 4) {  // waves 0..3 write q-stripes w
    const int b = bh >> 3, hh = bh & 7;
    const f32x4 lv = *(const f32x4*)&Ored[64 * 68 + w * 16 + lq * 4];
    f32x4 inv;
#pragma unroll
    for (int r = 0; r < 4; ++r) inv[r] = 1.f / lv[r];
#pragma unroll
    for (int dt = 0; dt < 4; ++dt) {
      const f32x4 o = *(const f32x4*)&Ored[(dt * 16 + lm) * 68 + w * 16 + lq * 4];
#pragma unroll
      for (int r = 0; r < 4; ++r)
        og[((size_t)b * 2048 + i0 + w * 16 + lq * 4 + r) * 512 + hh * 64 + dt * 16 + lm] =
            f2bf(o[r] * inv[r]);
    }
  }
}

// out = O @ Wproj^T + bproj, 128-tile (og/wproj bf16, bproj/out fp32)
__global__ __launch_bounds__(256) void k_gemm_proj(const unsigned short* __restrict__ og,
    const unsigned short* __restrict__ wjb, const float* __restrict__ bproj,
    float* __restrict__ out) {
  __shared__ short Asl[128 * 64], Wsl[128 * 64];
  f32x4 acc[4][4];
  const int m0 = blockIdx.y * 128, cc0 = blockIdx.x * 128;
  gemm128_mainloop(og + (size_t)m0 * 512, wjb + (size_t)cc0 * 512, Asl, Wsl, acc);
  const int tid = threadIdx.x, w = tid >> 6, lane = tid & 63, lm = lane & 15, lq = lane >> 4;
  const int wm = w >> 1, wn = w & 1;
#pragma unroll
  for (int nt = 0; nt < 4; ++nt) {
    const int cc = cc0 + wn * 64 + nt * 16 + lm;
    const float bias = bproj[cc];
#pragma unroll
    for (int mt = 0; mt < 4; ++mt) {
#pragma unroll
      for (int r = 0; r < 4; ++r) {
        const int m = m0 + wm * 64 + mt * 16 + lq * 4 + r;
        out[(size_t)m * 512 + cc] = acc[mt][nt][r] + bias;
      }
    }
  }
}

extern "C" void kernel_launch(void* const* d_in, const int* in_sizes, int n_in,
                              void* d_out, int out_size, void* d_ws, size_t ws_size,
                              hipStream_t stream) {
  const float* x     = (const float*)d_in[0];
  const float* pe    = (const float*)d_in[1];
  const float* wqkv  = (const float*)d_in[2];
  const float* wpos  = (const float*)d_in[3];
  const float* ub    = (const float*)d_in[4];
  const float* vb    = (const float*)d_in[5];
  const float* wproj = (const float*)d_in[6];
  const float* bproj = (const float*)d_in[7];
  float* out = (float*)d_out;
  unsigned short* ws = (unsigned short*)d_ws;

  const size_t SZ = (size_t)2 * 8 * 2048 * 64;  // one [B,H,N,HD] buffer (2M elems)
  unsigned short* qu   = ws;
  unsigned short* qv   = qu + SZ;
  unsigned short* kg   = qv + SZ;
  unsigned short* vt   = kg + SZ;   // [B,H,HD,N], written directly by qkvpos
  unsigned short* pos  = vt + SZ;
  unsigned short* og   = pos + SZ;
  unsigned short* cvtb = og + SZ;  // bf16: x | pe | wqkv | wpos | wproj
  unsigned short* xb   = cvtb;
  unsigned short* peb  = cvtb + 2097152;
  unsigned short* wqb  = cvtb + 4194304;
  unsigned short* wpb  = cvtb + 4980736;
  unsigned short* wjb  = cvtb + 5242880;

  dim3 blk(256);
  hipLaunchKernelGGL(k_cvt,         dim3(2688),   blk, 0, stream, x, pe, wqkv, wpos, wproj, cvtb);
  hipLaunchKernelGGL(k_gemm_qkvpos, dim3(16, 32), blk, 0, stream,
                     xb, peb, wqb, wpb, ub, vb, qu, qv, kg, vt, pos);
  hipLaunchKernelGGL(k_flash,       dim3(32, 16), dim3(512), 0, stream, qu, qv, kg, vt, pos, og);
  hipLaunchKernelGGL(k_gemm_proj,   dim3(4, 32),  blk, 0, stream, og, wjb, bproj, out);
}

// Round 12
// 198.580 us; speedup vs baseline: 1.5992x; 1.0067x over previous
//
#include <hip/hip_runtime.h>

// Problem constants: B=2, N=2048, C=512, H=8, HD=64
// Inputs fp32 (per reference); intermediates bf16 in ws; output fp32.
// R11 post-mortem: hand-written v_cvt_pk_bf16_f32 NaN'd (T12 catalog itself
// warns: don't hand-write cvt_pk; compiler path is faster anyway). k_flash
// reverted byte-for-byte to R10 (98.1us proven). This round's experiment:
// k_gemm_proj 64-row tiles -> 256 blocks = 1/CU (was 128 = 0.5/CU).
typedef __attribute__((ext_vector_type(8))) short bf16x8;
typedef __attribute__((ext_vector_type(4))) short bf16x4;
typedef __attribute__((ext_vector_type(4))) float f32x4;

__device__ __forceinline__ float bf2f(unsigned short u) {
  union { unsigned int i; float f; } c; c.i = ((unsigned int)u) << 16; return c.f;
}
__device__ __forceinline__ unsigned short f2bf(float x) {
  union { float f; unsigned int i; } c; c.f = x;
  return (unsigned short)((c.i + 0x7fffu + ((c.i >> 16) & 1u)) >> 16);
}
__device__ __forceinline__ unsigned int pk2(float a, float b) {
  return (unsigned int)f2bf(a) | ((unsigned int)f2bf(b) << 16);
}

__device__ __forceinline__ uint4 ld8f(const float* p) {
  const float4 a = *(const float4*)p;
  const float4 b = *(const float4*)(p + 4);
  uint4 r;
  r.x = (unsigned)f2bf(a.x) | ((unsigned)f2bf(a.y) << 16);
  r.y = (unsigned)f2bf(a.z) | ((unsigned)f2bf(a.w) << 16);
  r.z = (unsigned)f2bf(b.x) | ((unsigned)f2bf(b.y) << 16);
  r.w = (unsigned)f2bf(b.z) | ((unsigned)f2bf(b.w) << 16);
  return r;
}

// Async global->LDS, 16B per lane: HW writes lds_base + lane*16.
__device__ __forceinline__ void gload16(const unsigned short* g, short* l) {
  __builtin_amdgcn_global_load_lds((const __attribute__((address_space(1))) void*)g,
                                   (__attribute__((address_space(3))) void*)l, 16, 0, 0);
}

// fp32 -> bf16 pre-convert of x, pe, Wqkv, Wpos, Wproj (R11-proven).
__global__ __launch_bounds__(256) void k_cvt(const float* __restrict__ x,
    const float* __restrict__ pe, const float* __restrict__ wq,
    const float* __restrict__ wp, const float* __restrict__ wj,
    unsigned short* __restrict__ dst) {
  const long long i8 = ((long long)blockIdx.x * 256 + threadIdx.x) * 8;
  const float* src; long long off;
  if (i8 < 2097152)      { src = x;  off = i8; }
  else if (i8 < 4194304) { src = pe; off = i8 - 2097152; }
  else if (i8 < 4980736) { src = wq; off = i8 - 4194304; }
  else if (i8 < 5242880) { src = wp; off = i8 - 4980736; }
  else                   { src = wj; off = i8 - 5242880; }
  *(uint4*)&dst[i8] = ld8f(src + off);
}

// 128x128 NT GEMM mainloop (m97 ladder): 256 threads = 2x2 waves, each wave a
// 64x64 subtile (4x4 MFMA 16x16x32). Staging via global_load_lds width=16.
__device__ __forceinline__ void gemm128_mainloop(const unsigned short* __restrict__ Arow,
                                                 const unsigned short* __restrict__ Wrow,
                                                 short* Asl, short* Wsl, f32x4 acc[4][4]) {
  const int tid = threadIdx.x, w = tid >> 6, lane = tid & 63, lm = lane & 15, lq = lane >> 4;
  const int wm = w >> 1, wn = w & 1;
  const int lrow = lane >> 3;                       // 0..7 within an 8-row slab
  const int gcol = (((lane & 7) ^ lrow) * 8);       // swizzled source chunk
#pragma unroll
  for (int mt = 0; mt < 4; ++mt)
#pragma unroll
    for (int nt = 0; nt < 4; ++nt) acc[mt][nt] = (f32x4){0.f, 0.f, 0.f, 0.f};
#pragma unroll 1
  for (int kc = 0; kc < 512; kc += 64) {
    __syncthreads();  // prior iteration's frag reads done
#pragma unroll
    for (int ld = 0; ld < 4; ++ld) {
      const int rbase = w * 32 + ld * 8;
      gload16(&Arow[(size_t)(rbase + lrow) * 512 + kc + gcol], &Asl[rbase * 64]);
      gload16(&Wrow[(size_t)(rbase + lrow) * 512 + kc + gcol], &Wsl[rbase * 64]);
    }
    __syncthreads();  // staging visible (vmcnt drained by barrier)
#pragma unroll
    for (int kk = 0; kk < 2; ++kk) {
      const int pcs = ((kk * 4 + lq) ^ (lm & 7)) * 8;
      bf16x8 af[4], bfr[4];
#pragma unroll
      for (int mt = 0; mt < 4; ++mt)
        af[mt] = *(const bf16x8*)&Asl[(wm * 64 + mt * 16 + lm) * 64 + pcs];
#pragma unroll
      for (int nt = 0; nt < 4; ++nt)
        bfr[nt] = *(const bf16x8*)&Wsl[(wn * 64 + nt * 16 + lm) * 64 + pcs];
#pragma unroll
      for (int mt = 0; mt < 4; ++mt)
#pragma unroll
        for (int nt = 0; nt < 4; ++nt)
          acc[mt][nt] = __builtin_amdgcn_mfma_f32_16x16x32_bf16(af[mt], bfr[nt], acc[mt][nt], 0, 0, 0);
    }
  }
}

// Coalesced epilogue via LDS transpose buffer TT[128][130] bf16 (aliases the
// GEMM staging LDS). Phase A: acc (+optional bias, fp32 add BEFORE rounding)
// -> TT[m_local][cc_local]. Phase B: uint4 rows to dst[bh][n][d].
__device__ __forceinline__ void epi_rows(const f32x4 acc[4][4], const float* __restrict__ bias,
                                         short* TT, unsigned short* __restrict__ dst,
                                         int m0, int cc0) {
  const int tid = threadIdx.x, w = tid >> 6, lane = tid & 63, lm = lane & 15, lq = lane >> 4;
  const int wm = w >> 1, wn = w & 1;
  __syncthreads();  // prior LDS use (mainloop frags / previous phase B) done
#pragma unroll
  for (int mt = 0; mt < 4; ++mt)
#pragma unroll
    for (int nt = 0; nt < 4; ++nt) {
      const int ccl = wn * 64 + nt * 16 + lm;
      const float bb = bias ? bias[(cc0 + ccl) & 511] : 0.f;
#pragma unroll
      for (int r = 0; r < 4; ++r)
        TT[(wm * 64 + mt * 16 + lq * 4 + r) * 130 + ccl] = (short)f2bf(acc[mt][nt][r] + bb);
    }
  __syncthreads();  // TT visible
#pragma unroll
  for (int rr = 0; rr < 8; ++rr) {
    const int ml = rr * 16 + (tid >> 4), ccl = (tid & 15) * 8;
    const uint4 v = *(const uint4*)&TT[ml * 130 + ccl];
    const int m = m0 + ml, b = m >> 11, n = m & 2047;
    const int cc = cc0 + ccl, hh = (cc >> 6) & 7, d = cc & 63;
    *(uint4*)&dst[((size_t)(b * 8 + hh) * 2048 + n) * 64 + d] = v;
  }
}

// Transposed epilogue for the V section: TT[m][cc] read along m, emit
// vt[bh][d][n] rows (coalesced). Fuses the old k_transpose_v kernel.
__device__ __forceinline__ void epi_cols(const f32x4 acc[4][4], short* TT,
                                         unsigned short* __restrict__ vt,
                                         int m0, int cc0) {
  const int tid = threadIdx.x, w = tid >> 6, lane = tid & 63, lm = lane & 15, lq = lane >> 4;
  const int wm = w >> 1, wn = w & 1;
  __syncthreads();
#pragma unroll
  for (int mt = 0; mt < 4; ++mt)
#pragma unroll
    for (int nt = 0; nt < 4; ++nt) {
      const int ccl = wn * 64 + nt * 16 + lm;
#pragma unroll
      for (int r = 0; r < 4; ++r)
        TT[(wm * 64 + mt * 16 + lq * 4 + r) * 130 + ccl] = (short)f2bf(acc[mt][nt][r]);
    }
  __syncthreads();
  const int b = m0 >> 11;
#pragma unroll
  for (int ss = 0; ss < 8; ++ss) {
    const int ccl = ss * 16 + (tid >> 4), mch = (tid & 15) * 8;
    alignas(16) unsigned short tmp[8];
#pragma unroll
    for (int j = 0; j < 8; ++j) tmp[j] = (unsigned short)TT[(mch + j) * 130 + ccl];
    const int cc = cc0 + ccl, hh = (cc >> 6) & 7, d = cc & 63;
    const int n = (m0 & 2047) + mch;
    *(uint4*)&vt[((size_t)(b * 8 + hh) * 64 + d) * 2048 + n] = *(const uint4*)tmp;
  }
}

// Fused 128-tile: qkv = x @ Wqkv^T (cc0 < 1536) and pos = pe @ Wpos^T.
__global__ __launch_bounds__(256) void k_gemm_qkvpos(const unsigned short* __restrict__ xb,
    const unsigned short* __restrict__ peb, const unsigned short* __restrict__ wqb,
    const unsigned short* __restrict__ wpb, const float* __restrict__ ub,
    const float* __restrict__ vb, unsigned short* __restrict__ qu,
    unsigned short* __restrict__ qv, unsigned short* __restrict__ kg,
    unsigned short* __restrict__ vt, unsigned short* __restrict__ pos) {
  __shared__ short SB[16640];  // mainloop: A[0:8192)+W[8192:16384); epi: TT[128][130]
  f32x4 acc[4][4];
  const int m0 = blockIdx.y * 128, cc0 = blockIdx.x * 128;
  const unsigned short* Arow = (cc0 < 1536 ? xb : peb) + (size_t)m0 * 512;
  const unsigned short* Wrow = (cc0 < 1536) ? (wqb + (size_t)cc0 * 512)
                                            : (wpb + (size_t)(cc0 - 1536) * 512);
  gemm128_mainloop(Arow, Wrow, SB, SB + 8192, acc);
  const int sec = cc0 >> 9;  // block-uniform (cc0 multiple of 128)
  if (sec == 0) {
    epi_rows(acc, ub, SB, qu, m0, cc0);
    epi_rows(acc, vb, SB, qv, m0, cc0);
  } else if (sec == 1) {
    epi_rows(acc, nullptr, SB, kg, m0, cc0);
  } else if (sec == 2) {
    epi_cols(acc, SB, vt, m0, cc0);
  } else {
    epi_rows(acc, nullptr, SB, pos, m0, cc0);
  }
}

// Fused flash attention v9 (R10, 98.1us proven): async gload16 staging,
// XOR-swizzled unpadded LDS, 2 barriers/tile, v6 tile/wave decomposition.
__global__ __launch_bounds__(512, 4) void k_flash(const unsigned short* __restrict__ qu,
    const unsigned short* __restrict__ qv, const unsigned short* __restrict__ kg,
    const unsigned short* __restrict__ vt, const unsigned short* __restrict__ posg,
    unsigned short* __restrict__ og) {
  // LDS (shorts): Ks[2][64][64] @0; Vs[2][64][64] @8192; Pn[128][64] @16384;
  // T[65][84] @24576. 30036 shorts = 60072 B -> 2 blocks/CU.
  __shared__ short SB[30036];
  short* KsB = SB;
  short* VsB = SB + 8192;
  short* Pn  = SB + 16384;
  short* T   = SB + 24576;
  float* Ored = (float*)SB;  // epilogue alias: [65][68] f32, row 64 = lsum
  const int tid = threadIdx.x, w = tid >> 6, lane = tid & 63, lm = lane & 15, lq = lane >> 4;
  const int wk = w & 3;   // k-slice within tile
  const int h  = w >> 2;  // q-half (stripes {2h, 2h+1})
  const int sw = w >> 1;  // T-build stripe
  const int ph = w & 1;   // T-build phase-half
  // XCD-aware remap: each XCD owns bh pair {2*xcd, 2*xcd+1}, all 32 i-tiles.
  const int hw = blockIdx.x + 32 * blockIdx.y;
  const int xcd = hw & 7, idx = hw >> 3;
  const int bh = xcd * 2 + (idx & 1);
  const int i0 = (idx >> 1) * 64;
  const size_t bhs = (size_t)bh;
  const unsigned short* qub = qu + bhs * (2048 * 64);
  const unsigned short* qvb = qv + bhs * (2048 * 64);
  const unsigned short* pob = posg + bhs * (2048 * 64);
  // Swizzled-read constants (phys chunk = logical chunk ^ (row&7)):
  const int x7 = lm & 7;
  const int kc0 = (lq ^ x7) * 8, kc1 = ((lq + 4) ^ x7) * 8;          // K & main-Pn (row&7==lm&7)
  const int xe = (lm + 7) & 7;
  const int ec0 = (lq ^ xe) * 8, ec1 = ((lq + 4) ^ xe) * 8;          // edge-Pn (slot&7==(lm-1)&7)
  const int ve = (((2 * wk + (lq >> 1)) ^ x7) * 8) + (lq & 1) * 4;   // V frag b64
  const int r0c0 = (lq ^ 7) * 8, r0c1 = ((lq + 4) ^ 7) * 8;          // eb reload (slot&7==7)
  // Staging constants (gemm128's source-swizzle pattern):
  const int lrow = lane >> 3;
  const int gcol = ((lane & 7) ^ lrow) * 8;
  const unsigned short* ksrc = &kg[(bhs * 2048 + 8 * w + lrow) * 64 + gcol];
  const unsigned short* vsrc = &vt[(bhs * 64 + 8 * w + lrow) * 2048 + gcol];
  // (q+u) B-frags for this wave's two q-stripes (content scores).
  bf16x8 au[2][2];
#pragma unroll
  for (int qt = 0; qt < 2; ++qt) {
    const int qs = h * 2 + qt;
    au[qt][0] = *(const bf16x8*)&qub[(size_t)(i0 + qs * 16 + lm) * 64 + lq * 8];
    au[qt][1] = *(const bf16x8*)&qub[(size_t)(i0 + qs * 16 + lm) * 64 + 32 + lq * 8];
  }
  // (q+v) frags for T-build stripe sw, and edge rows (T row 64 = q_{i0+64}).
  const bf16x8 av0 = *(const bf16x8*)&qvb[(size_t)(i0 + sw * 16 + lm) * 64 + lq * 8];
  const bf16x8 av1 = *(const bf16x8*)&qvb[(size_t)(i0 + sw * 16 + lm) * 64 + 32 + lq * 8];
  const int rowe = min(i0 + 49 + lm, 2047);  // row 64 never read when i0==1984
  const bf16x8 ae0 = *(const bf16x8*)&qvb[(size_t)rowe * 64 + lq * 8];
  const bf16x8 ae1 = *(const bf16x8*)&qvb[(size_t)rowe * 64 + 32 + lq * 8];
  float lsum[2] = {0.f, 0.f};  // q = (h*2+qt)*16+lm, own k-slice partial
  f32x4 oacc[2][4];            // [qt][dt]: q=i0+(h*2+qt)*16+lq*4+r, d=dt*16+lm
#pragma unroll
  for (int ii = 0; ii < 2; ++ii)
#pragma unroll
    for (int jj = 0; jj < 4; ++jj) oacc[ii][jj] = (f32x4){0.f, 0.f, 0.f, 0.f};
  const int pb0 = 1983 - i0;  // === 7 mod 8 for all blocks (incl. i0=1984 -> -1)
  // Prologue: tile-0 K/V into buf0; Pn offsets 1..128 (16 aligned slabs,
  // 2/wave); eb (pos_{pb0}) direct from global for the edge col-0 lanes.
  gload16(ksrc, &KsB[w * 512]);
  gload16(vsrc, &VsB[w * 512]);
#pragma unroll
  for (int s = 0; s < 2; ++s) {
    const int u = 2 * w + s;
    const int slotb = (pb0 + 1 + 8 * u) & 127;
    const int grow = (pb0 + 1 + 8 * u + lrow + 4096) & 2047;
    gload16(&pob[(size_t)grow * 64 + gcol], &Pn[slotb * 64]);
  }
  bf16x8 eb0 = {}, eb1 = {};
  if (w == 1 && lm == 0) {
    const int g0 = (pb0 + 4096) & 2047;
    eb0 = *(const bf16x8*)&pob[(size_t)g0 * 64 + lq * 8];
    eb1 = *(const bf16x8*)&pob[(size_t)g0 * 64 + 32 + lq * 8];
  }
#pragma unroll 1
  for (int jt = 0; jt < 32; ++jt) {
    const int j0 = jt * 64;
    const int pb = pb0 + j0;
    const int nb = jt & 1;
    short* Ks = KsB + nb * 4096;
    short* Vs = VsB + nb * 4096;
    __syncthreads();  // B1: staging(jt) drained+visible; prior tile's PV reads done
    if (jt < 31) {    // async K/V staging for jt+1 into the other buffer
      const int jn = j0 + 64;
      gload16(ksrc + (size_t)jn * 64, &KsB[(nb ^ 1) * 4096 + w * 512]);
      gload16(vsrc + jn, &VsB[(nb ^ 1) * 4096 + w * 512]);
    }
    // Content scores, swapped operands: cacc[qt][r] =
    //   (q_{i0+(h*2+qt)*16+lm}+u) . K_{j0+wk*16+lq*4+r}
    const bf16x8 k0 = *(const bf16x8*)&Ks[(wk * 16 + lm) * 64 + kc0];
    const bf16x8 k1 = *(const bf16x8*)&Ks[(wk * 16 + lm) * 64 + kc1];
    f32x4 cacc[2];
#pragma unroll
    for (int qt = 0; qt < 2; ++qt) {
      cacc[qt] = __builtin_amdgcn_mfma_f32_16x16x32_bf16(k0, au[qt][0], (f32x4){0.f,0.f,0.f,0.f}, 0, 0, 0);
      cacc[qt] = __builtin_amdgcn_mfma_f32_16x16x32_bf16(k1, au[qt][1], cacc[qt], 0, 0, 0);
    }
    // T build: stripe sw rows qg=sw*16+lm over cols c=0..79, split by ph.
    // T[qg][c] = (q_{i0+qg}+v) . pos_{(pb + c + 49 - 16*sw) mod 2048}
    const int sbase = 49 - sw * 16;
    if (ph == 0) {
#pragma unroll
      for (int ct = 0; ct < 3; ++ct) {
        const int slot = (pb + sbase + ct * 16 + lm) & 127;
        const bf16x8 b0 = *(const bf16x8*)&Pn[slot * 64 + kc0];
        const bf16x8 b1 = *(const bf16x8*)&Pn[slot * 64 + kc1];
        f32x4 t0 = __builtin_amdgcn_mfma_f32_16x16x32_bf16(b0, av0, (f32x4){0.f,0.f,0.f,0.f}, 0, 0, 0);
        t0 = __builtin_amdgcn_mfma_f32_16x16x32_bf16(b1, av1, t0, 0, 0, 0);
        uint2 pk; pk.x = pk2(t0[0], t0[1]); pk.y = pk2(t0[2], t0[3]);
        *(uint2*)&T[(sw * 16 + lm) * 84 + ct * 16 + lq * 4] = pk;
      }
    } else {
#pragma unroll
      for (int ct = 3; ct < 5; ++ct) {
        const int slot = (pb + sbase + ct * 16 + lm) & 127;
        const bf16x8 b0 = *(const bf16x8*)&Pn[slot * 64 + kc0];
        const bf16x8 b1 = *(const bf16x8*)&Pn[slot * 64 + kc1];
        f32x4 t0 = __builtin_amdgcn_mfma_f32_16x16x32_bf16(b0, av0, (f32x4){0.f,0.f,0.f,0.f}, 0, 0, 0);
        t0 = __builtin_amdgcn_mfma_f32_16x16x32_bf16(b1, av1, t0, 0, 0, 0);
        uint2 pk; pk.x = pk2(t0[0], t0[1]); pk.y = pk2(t0[2], t0[3]);
        *(uint2*)&T[(sw * 16 + lm) * 84 + ct * 16 + lq * 4] = pk;
      }
      {  // edge row qg=64: T[64][c'] = (q_{i0+64}+v) . pos_{pb + c'};
         // ph1 waves cover col groups c' = sw*16 + 0..15. Col 0's pos row
         // (offset 0) comes from regs (its Pn slot was clobbered last tile).
        bf16x8 b0, b1;
        if (sw == 0 && lm == 0) {
          b0 = eb0; b1 = eb1;
        } else {
          const int slot = (pb + sw * 16 + lm) & 127;
          b0 = *(const bf16x8*)&Pn[slot * 64 + ec0];
          b1 = *(const bf16x8*)&Pn[slot * 64 + ec1];
        }
        f32x4 e0 = __builtin_amdgcn_mfma_f32_16x16x32_bf16(b0, ae0, (f32x4){0.f,0.f,0.f,0.f}, 0, 0, 0);
        e0 = __builtin_amdgcn_mfma_f32_16x16x32_bf16(b1, ae1, e0, 0, 0, 0);
        if (lm == 15) {
          uint2 pk; pk.x = pk2(e0[0], e0[1]); pk.y = pk2(e0[2], e0[3]);
          *(uint2*)&T[64 * 84 + sw * 16 + lq * 4] = pk;
        }
        if (sw == 0 && lm == 0) {  // reload eb = pos_{pb+64} before B2's clobber
          const int sl = (pb + 64) & 127;
          eb0 = *(const bf16x8*)&Pn[sl * 64 + r0c0];
          eb1 = *(const bf16x8*)&Pn[sl * 64 + r0c1];
        }
      }
    }
    __syncthreads();  // B2: T visible cross-wave; all Pn reads of this tile done
    if (jt < 31) {    // async Pn staging: rows pb+129..pb+192 (8 aligned slabs)
      const int slotb = (pb + 129 + 8 * w) & 127;
      const int grow = (pb + 129 + 8 * w + lrow + 4096) & 2047;
      gload16(&pob[(size_t)grow * 64 + gcol], &Pn[slotb * 64]);
    }
    // Gather pos addend + softmax-exp + in-lane bf16 pack (PV A-frags).
    const int diag = i0 - j0;
    const int jl0 = wk * 16 + lq * 4;
    bf16x4 pf[2];
    if (diag >= 64 || diag <= -128) {  // fast: delta uniform, no j==i+1
      const int du = (diag <= -128) ? 1 : 0;
      const int rm = lm + du;
#pragma unroll
      for (int qt = 0; qt < 2; ++qt) {
        const int rowa = (h * 2 + qt) * 16 + rm;
        const int base = (rowa == 64) ? (64 * 84 + jl0)
                                      : (rowa * 84 + 15 + jl0 - (rm & 15));
#pragma unroll
        for (int r = 0; r < 4; ++r) {
          const float pv = bf2f((unsigned short)T[base + r]);
          const float p = exp2f((cacc[qt][r] + pv) * 0.18033688f);
          lsum[qt] += p;
          pf[qt][r] = (short)f2bf(p);
        }
      }
    } else {  // boundary tiles (diag in {0,-64}): per-element delta/zero
#pragma unroll
      for (int qt = 0; qt < 2; ++qt) {
        const int qs = h * 2 + qt;
#pragma unroll
        for (int r = 0; r < 4; ++r) {
          const int jl = jl0 + r;
          const int d = (j0 - i0) + jl - (qs * 16 + lm);
          float pv;
          if (d == 1) {
            pv = 0.f;
          } else {
            const int rm2 = lm + ((d > 1) ? 1 : 0);
            const int rowa = qs * 16 + rm2;
            const int base = (rowa == 64) ? (64 * 84 + jl)
                                          : (rowa * 84 + 15 + jl - (rm2 & 15));
            pv = bf2f((unsigned short)T[base]);
          }
          const float p = exp2f((cacc[qt][r] + pv) * 0.18033688f);
          lsum[qt] += p;
          pf[qt][r] = (short)f2bf(p);
        }
      }
    }
    // PV: K=16 MFMA, P in A-frag layout; V B-frag = wave's k-slice (swizzled).
#pragma unroll
    for (int dt = 0; dt < 4; ++dt) {
      const bf16x4 vf = *(const bf16x4*)&Vs[(dt * 16 + lm) * 64 + ve];
      oacc[0][dt] = __builtin_amdgcn_mfma_f32_16x16x16bf16_1k(pf[0], vf, oacc[0][dt], 0, 0, 0);
      oacc[1][dt] = __builtin_amdgcn_mfma_f32_16x16x16bf16_1k(pf[1], vf, oacc[1][dt], 0, 0, 0);
    }
  }
  // Epilogue: reduce k-slice partials across the 4 wk-waves of each q-half.
#pragma unroll
  for (int qt = 0; qt < 2; ++qt) {  // sum the 4 lq lanes (k within slice)
    lsum[qt] += __shfl_xor(lsum[qt], 16, 64);
    lsum[qt] += __shfl_xor(lsum[qt], 32, 64);
  }
  __syncthreads();  // PV done; stray DMAs drained; Ored alias safe
  if (wk == 0) {
#pragma unroll
    for (int qt = 0; qt < 2; ++qt) {
      const int qc = (h * 2 + qt) * 16;
#pragma unroll
      for (int dt = 0; dt < 4; ++dt)
        *(f32x4*)&Ored[(dt * 16 + lm) * 68 + qc + lq * 4] = oacc[qt][dt];
      if (lq == 0) Ored[64 * 68 + qc + lm] = lsum[qt];
    }
  }
  __syncthreads();
#pragma unroll 1
  for (int r = 1; r < 4; ++r) {
    if (wk == r) {
#pragma unroll
      for (int qt = 0; qt < 2; ++qt) {
        const int qc = (h * 2 + qt) * 16;
#pragma unroll
        for (int dt = 0; dt < 4; ++dt) {
          f32x4 o = *(const f32x4*)&Ored[(dt * 16 + lm) * 68 + qc + lq * 4];
          o += oacc[qt][dt];
          *(f32x4*)&Ored[(dt * 16 + lm) * 68 + qc + lq * 4] = o;
        }
        if (lq == 0) Ored[64 * 68 + qc + lm] += lsum[qt];
      }
    }
    __syncthreads();
  }
  if (w < 4) {  // waves 0..3 write q-stripes w
    const int b = bh >> 3, hh = bh & 7;
    const f32x4 lv = *(const f32x4*)&Ored[64 * 68 + w * 16 + lq * 4];
    f32x4 inv;
#pragma unroll
    for (int r = 0; r < 4; ++r) inv[r] = 1.f / lv[r];
#pragma unroll
    for (int dt = 0; dt < 4; ++dt) {
      const f32x4 o = *(const f32x4*)&Ored[(dt * 16 + lm) * 68 + w * 16 + lq * 4];
#pragma unroll
      for (int r = 0; r < 4; ++r)
        og[((size_t)b * 2048 + i0 + w * 16 + lq * 4 + r) * 512 + hh * 64 + dt * 16 + lm] =
            f2bf(o[r] * inv[r]);
    }
  }
}

// out = O @ Wproj^T + bproj, 64x128 tiles -> grid (4,64) = 256 blocks = 1/CU
// (was 128x128 -> 128 blocks = 0.5/CU: half the GPU idle). 4 waves each own a
// 64x32 strip (acc[4][2]); same staging/swizzle formulas as gemm128 (row
// stride 64 preserved), same K order -> bit-identical accumulation.
__global__ __launch_bounds__(256) void k_gemm_proj(const unsigned short* __restrict__ og,
    const unsigned short* __restrict__ wjb, const float* __restrict__ bproj,
    float* __restrict__ out) {
  __shared__ short Asl[64 * 64], Wsl[128 * 64];
  f32x4 acc[4][2];
  const int m0 = blockIdx.y * 64, cc0 = blockIdx.x * 128;
  const unsigned short* Arow = og + (size_t)m0 * 512;
  const unsigned short* Wrow = wjb + (size_t)cc0 * 512;
  const int tid = threadIdx.x, w = tid >> 6, lane = tid & 63, lm = lane & 15, lq = lane >> 4;
  const int lrow = lane >> 3;
  const int gcol = (((lane & 7) ^ lrow) * 8);
#pragma unroll
  for (int mt = 0; mt < 4; ++mt)
#pragma unroll
    for (int nt = 0; nt < 2; ++nt) acc[mt][nt] = (f32x4){0.f, 0.f, 0.f, 0.f};
#pragma unroll 1
  for (int kc = 0; kc < 512; kc += 64) {
    __syncthreads();
#pragma unroll
    for (int ld = 0; ld < 2; ++ld) {  // A: 64 rows (16/wave)
      const int rbase = w * 16 + ld * 8;
      gload16(&Arow[(size_t)(rbase + lrow) * 512 + kc + gcol], &Asl[rbase * 64]);
    }
#pragma unroll
    for (int ld = 0; ld < 4; ++ld) {  // W: 128 rows (32/wave)
      const int rbase = w * 32 + ld * 8;
      gload16(&Wrow[(size_t)(rbase + lrow) * 512 + kc + gcol], &Wsl[rbase * 64]);
    }
    __syncthreads();
#pragma unroll
    for (int kk = 0; kk < 2; ++kk) {
      const int pcs = ((kk * 4 + lq) ^ (lm & 7)) * 8;
      bf16x8 af[4], bfr[2];
#pragma unroll
      for (int mt = 0; mt < 4; ++mt)
        af[mt] = *(const bf16x8*)&Asl[(mt * 16 + lm) * 64 + pcs];
#pragma unroll
      for (int nt = 0; nt < 2; ++nt)
        bfr[nt] = *(const bf16x8*)&Wsl[(w * 32 + nt * 16 + lm) * 64 + pcs];
#pragma unroll
      for (int mt = 0; mt < 4; ++mt)
#pragma unroll
        for (int nt = 0; nt < 2; ++nt)
          acc[mt][nt] = __builtin_amdgcn_mfma_f32_16x16x32_bf16(af[mt], bfr[nt], acc[mt][nt], 0, 0, 0);
    }
  }
#pragma unroll
  for (int nt = 0; nt < 2; ++nt) {
    const int cc = cc0 + w * 32 + nt * 16 + lm;
    const float bias = bproj[cc];
#pragma unroll
    for (int mt = 0; mt < 4; ++mt) {
#pragma unroll
      for (int r = 0; r < 4; ++r) {
        const int m = m0 + mt * 16 + lq * 4 + r;
        out[(size_t)m * 512 + cc] = acc[mt][nt][r] + bias;
      }
    }
  }
}

extern "C" void kernel_launch(void* const* d_in, const int* in_sizes, int n_in,
                              void* d_out, int out_size, void* d_ws, size_t ws_size,
                              hipStream_t stream) {
  const float* x     = (const float*)d_in[0];
  const float* pe    = (const float*)d_in[1];
  const float* wqkv  = (const float*)d_in[2];
  const float* wpos  = (const float*)d_in[3];
  const float* ub    = (const float*)d_in[4];
  const float* vb    = (const float*)d_in[5];
  const float* wproj = (const float*)d_in[6];
  const float* bproj = (const float*)d_in[7];
  float* out = (float*)d_out;
  unsigned short* ws = (unsigned short*)d_ws;

  const size_t SZ = (size_t)2 * 8 * 2048 * 64;  // one [B,H,N,HD] buffer (2M elems)
  unsigned short* qu   = ws;
  unsigned short* qv   = qu + SZ;
  unsigned short* kg   = qv + SZ;
  unsigned short* vt   = kg + SZ;   // [B,H,HD,N], written directly by qkvpos
  unsigned short* pos  = vt + SZ;
  unsigned short* og   = pos + SZ;
  unsigned short* cvtb = og + SZ;  // bf16: x | pe | wqkv | wpos | wproj
  unsigned short* xb   = cvtb;
  unsigned short* peb  = cvtb + 2097152;
  unsigned short* wqb  = cvtb + 4194304;
  unsigned short* wpb  = cvtb + 4980736;
  unsigned short* wjb  = cvtb + 5242880;

  dim3 blk(256);
  hipLaunchKernelGGL(k_cvt,         dim3(2688),   blk, 0, stream, x, pe, wqkv, wpos, wproj, cvtb);
  hipLaunchKernelGGL(k_gemm_qkvpos, dim3(16, 32), blk, 0, stream,
                     xb, peb, wqb, wpb, ub, vb, qu, qv, kg, vt, pos);
  hipLaunchKernelGGL(k_flash,       dim3(32, 16), dim3(512), 0, stream, qu, qv, kg, vt, pos, og);
  hipLaunchKernelGGL(k_gemm_proj,   dim3(4, 64),  blk, 0, stream, og, wjb, bproj, out);
}

// Round 13
// 193.581 us; speedup vs baseline: 1.6405x; 1.0258x over previous
//
#include <hip/hip_runtime.h>
#include <hip/hip_bf16.h>

// Problem constants: B=2, N=2048, C=512, H=8, HD=64
// Inputs fp32 (per reference); intermediates bf16 in ws; output fp32.
// R12 post-mortem: proj 256-block rebalance kept (+1.3us). This round:
// f2bf -> compiler cast (__float2bfloat16, RNE = bit-identical to the old
// integer rounding). T12/m240: compiler-cast beats hand-asm cvt_pk by 37%;
// R11's NaN was the hand-asm path. ~110 of ~200 VALU ops/thread/tile in
// k_flash were hand-rolled rounding; cast lets codegen emit HW cvt.
typedef __attribute__((ext_vector_type(8))) short bf16x8;
typedef __attribute__((ext_vector_type(4))) short bf16x4;
typedef __attribute__((ext_vector_type(4))) float f32x4;

__device__ __forceinline__ float bf2f(unsigned short u) {
  union { unsigned int i; float f; } c; c.i = ((unsigned int)u) << 16; return c.f;
}
__device__ __forceinline__ unsigned short f2bf(float x) {
  __hip_bfloat16 h = __float2bfloat16(x);  // RNE, bit-identical to manual path
  unsigned short u;
  __builtin_memcpy(&u, &h, 2);
  return u;
}
__device__ __forceinline__ unsigned int pk2(float a, float b) {
  return (unsigned int)f2bf(a) | ((unsigned int)f2bf(b) << 16);
}

__device__ __forceinline__ uint4 ld8f(const float* p) {
  const float4 a = *(const float4*)p;
  const float4 b = *(const float4*)(p + 4);
  uint4 r;
  r.x = pk2(a.x, a.y);
  r.y = pk2(a.z, a.w);
  r.z = pk2(b.x, b.y);
  r.w = pk2(b.z, b.w);
  return r;
}

// Async global->LDS, 16B per lane: HW writes lds_base + lane*16.
__device__ __forceinline__ void gload16(const unsigned short* g, short* l) {
  __builtin_amdgcn_global_load_lds((const __attribute__((address_space(1))) void*)g,
                                   (__attribute__((address_space(3))) void*)l, 16, 0, 0);
}

// fp32 -> bf16 pre-convert of x, pe, Wqkv, Wpos, Wproj (R11-proven).
__global__ __launch_bounds__(256) void k_cvt(const float* __restrict__ x,
    const float* __restrict__ pe, const float* __restrict__ wq,
    const float* __restrict__ wp, const float* __restrict__ wj,
    unsigned short* __restrict__ dst) {
  const long long i8 = ((long long)blockIdx.x * 256 + threadIdx.x) * 8;
  const float* src; long long off;
  if (i8 < 2097152)      { src = x;  off = i8; }
  else if (i8 < 4194304) { src = pe; off = i8 - 2097152; }
  else if (i8 < 4980736) { src = wq; off = i8 - 4194304; }
  else if (i8 < 5242880) { src = wp; off = i8 - 4980736; }
  else                   { src = wj; off = i8 - 5242880; }
  *(uint4*)&dst[i8] = ld8f(src + off);
}

// 128x128 NT GEMM mainloop (m97 ladder): 256 threads = 2x2 waves, each wave a
// 64x64 subtile (4x4 MFMA 16x16x32). Staging via global_load_lds width=16.
__device__ __forceinline__ void gemm128_mainloop(const unsigned short* __restrict__ Arow,
                                                 const unsigned short* __restrict__ Wrow,
                                                 short* Asl, short* Wsl, f32x4 acc[4][4]) {
  const int tid = threadIdx.x, w = tid >> 6, lane = tid & 63, lm = lane & 15, lq = lane >> 4;
  const int wm = w >> 1, wn = w & 1;
  const int lrow = lane >> 3;                       // 0..7 within an 8-row slab
  const int gcol = (((lane & 7) ^ lrow) * 8);       // swizzled source chunk
#pragma unroll
  for (int mt = 0; mt < 4; ++mt)
#pragma unroll
    for (int nt = 0; nt < 4; ++nt) acc[mt][nt] = (f32x4){0.f, 0.f, 0.f, 0.f};
#pragma unroll 1
  for (int kc = 0; kc < 512; kc += 64) {
    __syncthreads();  // prior iteration's frag reads done
#pragma unroll
    for (int ld = 0; ld < 4; ++ld) {
      const int rbase = w * 32 + ld * 8;
      gload16(&Arow[(size_t)(rbase + lrow) * 512 + kc + gcol], &Asl[rbase * 64]);
      gload16(&Wrow[(size_t)(rbase + lrow) * 512 + kc + gcol], &Wsl[rbase * 64]);
    }
    __syncthreads();  // staging visible (vmcnt drained by barrier)
#pragma unroll
    for (int kk = 0; kk < 2; ++kk) {
      const int pcs = ((kk * 4 + lq) ^ (lm & 7)) * 8;
      bf16x8 af[4], bfr[4];
#pragma unroll
      for (int mt = 0; mt < 4; ++mt)
        af[mt] = *(const bf16x8*)&Asl[(wm * 64 + mt * 16 + lm) * 64 + pcs];
#pragma unroll
      for (int nt = 0; nt < 4; ++nt)
        bfr[nt] = *(const bf16x8*)&Wsl[(wn * 64 + nt * 16 + lm) * 64 + pcs];
#pragma unroll
      for (int mt = 0; mt < 4; ++mt)
#pragma unroll
        for (int nt = 0; nt < 4; ++nt)
          acc[mt][nt] = __builtin_amdgcn_mfma_f32_16x16x32_bf16(af[mt], bfr[nt], acc[mt][nt], 0, 0, 0);
    }
  }
}

// Coalesced epilogue via LDS transpose buffer TT[128][130] bf16 (aliases the
// GEMM staging LDS). Phase A: acc (+optional bias, fp32 add BEFORE rounding)
// -> TT[m_local][cc_local]. Phase B: uint4 rows to dst[bh][n][d].
__device__ __forceinline__ void epi_rows(const f32x4 acc[4][4], const float* __restrict__ bias,
                                         short* TT, unsigned short* __restrict__ dst,
                                         int m0, int cc0) {
  const int tid = threadIdx.x, w = tid >> 6, lane = tid & 63, lm = lane & 15, lq = lane >> 4;
  const int wm = w >> 1, wn = w & 1;
  __syncthreads();  // prior LDS use (mainloop frags / previous phase B) done
#pragma unroll
  for (int mt = 0; mt < 4; ++mt)
#pragma unroll
    for (int nt = 0; nt < 4; ++nt) {
      const int ccl = wn * 64 + nt * 16 + lm;
      const float bb = bias ? bias[(cc0 + ccl) & 511] : 0.f;
#pragma unroll
      for (int r = 0; r < 4; ++r)
        TT[(wm * 64 + mt * 16 + lq * 4 + r) * 130 + ccl] = (short)f2bf(acc[mt][nt][r] + bb);
    }
  __syncthreads();  // TT visible
#pragma unroll
  for (int rr = 0; rr < 8; ++rr) {
    const int ml = rr * 16 + (tid >> 4), ccl = (tid & 15) * 8;
    const uint4 v = *(const uint4*)&TT[ml * 130 + ccl];
    const int m = m0 + ml, b = m >> 11, n = m & 2047;
    const int cc = cc0 + ccl, hh = (cc >> 6) & 7, d = cc & 63;
    *(uint4*)&dst[((size_t)(b * 8 + hh) * 2048 + n) * 64 + d] = v;
  }
}

// Transposed epilogue for the V section: TT[m][cc] read along m, emit
// vt[bh][d][n] rows (coalesced). Fuses the old k_transpose_v kernel.
__device__ __forceinline__ void epi_cols(const f32x4 acc[4][4], short* TT,
                                         unsigned short* __restrict__ vt,
                                         int m0, int cc0) {
  const int tid = threadIdx.x, w = tid >> 6, lane = tid & 63, lm = lane & 15, lq = lane >> 4;
  const int wm = w >> 1, wn = w & 1;
  __syncthreads();
#pragma unroll
  for (int mt = 0; mt < 4; ++mt)
#pragma unroll
    for (int nt = 0; nt < 4; ++nt) {
      const int ccl = wn * 64 + nt * 16 + lm;
#pragma unroll
      for (int r = 0; r < 4; ++r)
        TT[(wm * 64 + mt * 16 + lq * 4 + r) * 130 + ccl] = (short)f2bf(acc[mt][nt][r]);
    }
  __syncthreads();
  const int b = m0 >> 11;
#pragma unroll
  for (int ss = 0; ss < 8; ++ss) {
    const int ccl = ss * 16 + (tid >> 4), mch = (tid & 15) * 8;
    alignas(16) unsigned short tmp[8];
#pragma unroll
    for (int j = 0; j < 8; ++j) tmp[j] = (unsigned short)TT[(mch + j) * 130 + ccl];
    const int cc = cc0 + ccl, hh = (cc >> 6) & 7, d = cc & 63;
    const int n = (m0 & 2047) + mch;
    *(uint4*)&vt[((size_t)(b * 8 + hh) * 64 + d) * 2048 + n] = *(const uint4*)tmp;
  }
}

// Fused 128-tile: qkv = x @ Wqkv^T (cc0 < 1536) and pos = pe @ Wpos^T.
__global__ __launch_bounds__(256) void k_gemm_qkvpos(const unsigned short* __restrict__ xb,
    const unsigned short* __restrict__ peb, const unsigned short* __restrict__ wqb,
    const unsigned short* __restrict__ wpb, const float* __restrict__ ub,
    const float* __restrict__ vb, unsigned short* __restrict__ qu,
    unsigned short* __restrict__ qv, unsigned short* __restrict__ kg,
    unsigned short* __restrict__ vt, unsigned short* __restrict__ pos) {
  __shared__ short SB[16640];  // mainloop: A[0:8192)+W[8192:16384); epi: TT[128][130]
  f32x4 acc[4][4];
  const int m0 = blockIdx.y * 128, cc0 = blockIdx.x * 128;
  const unsigned short* Arow = (cc0 < 1536 ? xb : peb) + (size_t)m0 * 512;
  const unsigned short* Wrow = (cc0 < 1536) ? (wqb + (size_t)cc0 * 512)
                                            : (wpb + (size_t)(cc0 - 1536) * 512);
  gemm128_mainloop(Arow, Wrow, SB, SB + 8192, acc);
  const int sec = cc0 >> 9;  // block-uniform (cc0 multiple of 128)
  if (sec == 0) {
    epi_rows(acc, ub, SB, qu, m0, cc0);
    epi_rows(acc, vb, SB, qv, m0, cc0);
  } else if (sec == 1) {
    epi_rows(acc, nullptr, SB, kg, m0, cc0);
  } else if (sec == 2) {
    epi_cols(acc, SB, vt, m0, cc0);
  } else {
    epi_rows(acc, nullptr, SB, pos, m0, cc0);
  }
}

// Fused flash attention v9 (R10, 98.1us proven): async gload16 staging,
// XOR-swizzled unpadded LDS, 2 barriers/tile, v6 tile/wave decomposition.
// v11 delta: f2bf/pk2 now compile to HW bf16 conversion (see header comment).
__global__ __launch_bounds__(512, 4) void k_flash(const unsigned short* __restrict__ qu,
    const unsigned short* __restrict__ qv, const unsigned short* __restrict__ kg,
    const unsigned short* __restrict__ vt, const unsigned short* __restrict__ posg,
    unsigned short* __restrict__ og) {
  // LDS (shorts): Ks[2][64][64] @0; Vs[2][64][64] @8192; Pn[128][64] @16384;
  // T[65][84] @24576. 30036 shorts = 60072 B -> 2 blocks/CU.
  __shared__ short SB[30036];
  short* KsB = SB;
  short* VsB = SB + 8192;
  short* Pn  = SB + 16384;
  short* T   = SB + 24576;
  float* Ored = (float*)SB;  // epilogue alias: [65][68] f32, row 64 = lsum
  const int tid = threadIdx.x, w = tid >> 6, lane = tid & 63, lm = lane & 15, lq = lane >> 4;
  const int wk = w & 3;   // k-slice within tile
  const int h  = w >> 2;  // q-half (stripes {2h, 2h+1})
  const int sw = w >> 1;  // T-build stripe
  const int ph = w & 1;   // T-build phase-half
  // XCD-aware remap: each XCD owns bh pair {2*xcd, 2*xcd+1}, all 32 i-tiles.
  const int hw = blockIdx.x + 32 * blockIdx.y;
  const int xcd = hw & 7, idx = hw >> 3;
  const int bh = xcd * 2 + (idx & 1);
  const int i0 = (idx >> 1) * 64;
  const size_t bhs = (size_t)bh;
  const unsigned short* qub = qu + bhs * (2048 * 64);
  const unsigned short* qvb = qv + bhs * (2048 * 64);
  const unsigned short* pob = posg + bhs * (2048 * 64);
  // Swizzled-read constants (phys chunk = logical chunk ^ (row&7)):
  const int x7 = lm & 7;
  const int kc0 = (lq ^ x7) * 8, kc1 = ((lq + 4) ^ x7) * 8;          // K & main-Pn (row&7==lm&7)
  const int xe = (lm + 7) & 7;
  const int ec0 = (lq ^ xe) * 8, ec1 = ((lq + 4) ^ xe) * 8;          // edge-Pn (slot&7==(lm-1)&7)
  const int ve = (((2 * wk + (lq >> 1)) ^ x7) * 8) + (lq & 1) * 4;   // V frag b64
  const int r0c0 = (lq ^ 7) * 8, r0c1 = ((lq + 4) ^ 7) * 8;          // eb reload (slot&7==7)
  // Staging constants (gemm128's source-swizzle pattern):
  const int lrow = lane >> 3;
  const int gcol = ((lane & 7) ^ lrow) * 8;
  const unsigned short* ksrc = &kg[(bhs * 2048 + 8 * w + lrow) * 64 + gcol];
  const unsigned short* vsrc = &vt[(bhs * 64 + 8 * w + lrow) * 2048 + gcol];
  // (q+u) B-frags for this wave's two q-stripes (content scores).
  bf16x8 au[2][2];
#pragma unroll
  for (int qt = 0; qt < 2; ++qt) {
    const int qs = h * 2 + qt;
    au[qt][0] = *(const bf16x8*)&qub[(size_t)(i0 + qs * 16 + lm) * 64 + lq * 8];
    au[qt][1] = *(const bf16x8*)&qub[(size_t)(i0 + qs * 16 + lm) * 64 + 32 + lq * 8];
  }
  // (q+v) frags for T-build stripe sw, and edge rows (T row 64 = q_{i0+64}).
  const bf16x8 av0 = *(const bf16x8*)&qvb[(size_t)(i0 + sw * 16 + lm) * 64 + lq * 8];
  const bf16x8 av1 = *(const bf16x8*)&qvb[(size_t)(i0 + sw * 16 + lm) * 64 + 32 + lq * 8];
  const int rowe = min(i0 + 49 + lm, 2047);  // row 64 never read when i0==1984
  const bf16x8 ae0 = *(const bf16x8*)&qvb[(size_t)rowe * 64 + lq * 8];
  const bf16x8 ae1 = *(const bf16x8*)&qvb[(size_t)rowe * 64 + 32 + lq * 8];
  float lsum[2] = {0.f, 0.f};  // q = (h*2+qt)*16+lm, own k-slice partial
  f32x4 oacc[2][4];            // [qt][dt]: q=i0+(h*2+qt)*16+lq*4+r, d=dt*16+lm
#pragma unroll
  for (int ii = 0; ii < 2; ++ii)
#pragma unroll
    for (int jj = 0; jj < 4; ++jj) oacc[ii][jj] = (f32x4){0.f, 0.f, 0.f, 0.f};
  const int pb0 = 1983 - i0;  // === 7 mod 8 for all blocks (incl. i0=1984 -> -1)
  // Prologue: tile-0 K/V into buf0; Pn offsets 1..128 (16 aligned slabs,
  // 2/wave); eb (pos_{pb0}) direct from global for the edge col-0 lanes.
  gload16(ksrc, &KsB[w * 512]);
  gload16(vsrc, &VsB[w * 512]);
#pragma unroll
  for (int s = 0; s < 2; ++s) {
    const int u = 2 * w + s;
    const int slotb = (pb0 + 1 + 8 * u) & 127;
    const int grow = (pb0 + 1 + 8 * u + lrow + 4096) & 2047;
    gload16(&pob[(size_t)grow * 64 + gcol], &Pn[slotb * 64]);
  }
  bf16x8 eb0 = {}, eb1 = {};
  if (w == 1 && lm == 0) {
    const int g0 = (pb0 + 4096) & 2047;
    eb0 = *(const bf16x8*)&pob[(size_t)g0 * 64 + lq * 8];
    eb1 = *(const bf16x8*)&pob[(size_t)g0 * 64 + 32 + lq * 8];
  }
#pragma unroll 1
  for (int jt = 0; jt < 32; ++jt) {
    const int j0 = jt * 64;
    const int pb = pb0 + j0;
    const int nb = jt & 1;
    short* Ks = KsB + nb * 4096;
    short* Vs = VsB + nb * 4096;
    __syncthreads();  // B1: staging(jt) drained+visible; prior tile's PV reads done
    if (jt < 31) {    // async K/V staging for jt+1 into the other buffer
      const int jn = j0 + 64;
      gload16(ksrc + (size_t)jn * 64, &KsB[(nb ^ 1) * 4096 + w * 512]);
      gload16(vsrc + jn, &VsB[(nb ^ 1) * 4096 + w * 512]);
    }
    // Content scores, swapped operands: cacc[qt][r] =
    //   (q_{i0+(h*2+qt)*16+lm}+u) . K_{j0+wk*16+lq*4+r}
    const bf16x8 k0 = *(const bf16x8*)&Ks[(wk * 16 + lm) * 64 + kc0];
    const bf16x8 k1 = *(const bf16x8*)&Ks[(wk * 16 + lm) * 64 + kc1];
    f32x4 cacc[2];
#pragma unroll
    for (int qt = 0; qt < 2; ++qt) {
      cacc[qt] = __builtin_amdgcn_mfma_f32_16x16x32_bf16(k0, au[qt][0], (f32x4){0.f,0.f,0.f,0.f}, 0, 0, 0);
      cacc[qt] = __builtin_amdgcn_mfma_f32_16x16x32_bf16(k1, au[qt][1], cacc[qt], 0, 0, 0);
    }
    // T build: stripe sw rows qg=sw*16+lm over cols c=0..79, split by ph.
    // T[qg][c] = (q_{i0+qg}+v) . pos_{(pb + c + 49 - 16*sw) mod 2048}
    const int sbase = 49 - sw * 16;
    if (ph == 0) {
#pragma unroll
      for (int ct = 0; ct < 3; ++ct) {
        const int slot = (pb + sbase + ct * 16 + lm) & 127;
        const bf16x8 b0 = *(const bf16x8*)&Pn[slot * 64 + kc0];
        const bf16x8 b1 = *(const bf16x8*)&Pn[slot * 64 + kc1];
        f32x4 t0 = __builtin_amdgcn_mfma_f32_16x16x32_bf16(b0, av0, (f32x4){0.f,0.f,0.f,0.f}, 0, 0, 0);
        t0 = __builtin_amdgcn_mfma_f32_16x16x32_bf16(b1, av1, t0, 0, 0, 0);
        uint2 pk; pk.x = pk2(t0[0], t0[1]); pk.y = pk2(t0[2], t0[3]);
        *(uint2*)&T[(sw * 16 + lm) * 84 + ct * 16 + lq * 4] = pk;
      }
    } else {
#pragma unroll
      for (int ct = 3; ct < 5; ++ct) {
        const int slot = (pb + sbase + ct * 16 + lm) & 127;
        const bf16x8 b0 = *(const bf16x8*)&Pn[slot * 64 + kc0];
        const bf16x8 b1 = *(const bf16x8*)&Pn[slot * 64 + kc1];
        f32x4 t0 = __builtin_amdgcn_mfma_f32_16x16x32_bf16(b0, av0, (f32x4){0.f,0.f,0.f,0.f}, 0, 0, 0);
        t0 = __builtin_amdgcn_mfma_f32_16x16x32_bf16(b1, av1, t0, 0, 0, 0);
        uint2 pk; pk.x = pk2(t0[0], t0[1]); pk.y = pk2(t0[2], t0[3]);
        *(uint2*)&T[(sw * 16 + lm) * 84 + ct * 16 + lq * 4] = pk;
      }
      {  // edge row qg=64: T[64][c'] = (q_{i0+64}+v) . pos_{pb + c'};
         // ph1 waves cover col groups c' = sw*16 + 0..15. Col 0's pos row
         // (offset 0) comes from regs (its Pn slot was clobbered last tile).
        bf16x8 b0, b1;
        if (sw == 0 && lm == 0) {
          b0 = eb0; b1 = eb1;
        } else {
          const int slot = (pb + sw * 16 + lm) & 127;
          b0 = *(const bf16x8*)&Pn[slot * 64 + ec0];
          b1 = *(const bf16x8*)&Pn[slot * 64 + ec1];
        }
        f32x4 e0 = __builtin_amdgcn_mfma_f32_16x16x32_bf16(b0, ae0, (f32x4){0.f,0.f,0.f,0.f}, 0, 0, 0);
        e0 = __builtin_amdgcn_mfma_f32_16x16x32_bf16(b1, ae1, e0, 0, 0, 0);
        if (lm == 15) {
          uint2 pk; pk.x = pk2(e0[0], e0[1]); pk.y = pk2(e0[2], e0[3]);
          *(uint2*)&T[64 * 84 + sw * 16 + lq * 4] = pk;
        }
        if (sw == 0 && lm == 0) {  // reload eb = pos_{pb+64} before B2's clobber
          const int sl = (pb + 64) & 127;
          eb0 = *(const bf16x8*)&Pn[sl * 64 + r0c0];
          eb1 = *(const bf16x8*)&Pn[sl * 64 + r0c1];
        }
      }
    }
    __syncthreads();  // B2: T visible cross-wave; all Pn reads of this tile done
    if (jt < 31) {    // async Pn staging: rows pb+129..pb+192 (8 aligned slabs)
      const int slotb = (pb + 129 + 8 * w) & 127;
      const int grow = (pb + 129 + 8 * w + lrow + 4096) & 2047;
      gload16(&pob[(size_t)grow * 64 + gcol], &Pn[slotb * 64]);
    }
    // Gather pos addend + softmax-exp + in-lane bf16 pack (PV A-frags).
    const int diag = i0 - j0;
    const int jl0 = wk * 16 + lq * 4;
    bf16x4 pf[2];
    if (diag >= 64 || diag <= -128) {  // fast: delta uniform, no j==i+1
      const int du = (diag <= -128) ? 1 : 0;
      const int rm = lm + du;
#pragma unroll
      for (int qt = 0; qt < 2; ++qt) {
        const int rowa = (h * 2 + qt) * 16 + rm;
        const int base = (rowa == 64) ? (64 * 84 + jl0)
                                      : (rowa * 84 + 15 + jl0 - (rm & 15));
#pragma unroll
        for (int r = 0; r < 4; ++r) {
          const float pv = bf2f((unsigned short)T[base + r]);
          const float p = exp2f((cacc[qt][r] + pv) * 0.18033688f);
          lsum[qt] += p;
          pf[qt][r] = (short)f2bf(p);
        }
      }
    } else {  // boundary tiles (diag in {0,-64}): per-element delta/zero
#pragma unroll
      for (int qt = 0; qt < 2; ++qt) {
        const int qs = h * 2 + qt;
#pragma unroll
        for (int r = 0; r < 4; ++r) {
          const int jl = jl0 + r;
          const int d = (j0 - i0) + jl - (qs * 16 + lm);
          float pv;
          if (d == 1) {
            pv = 0.f;
          } else {
            const int rm2 = lm + ((d > 1) ? 1 : 0);
            const int rowa = qs * 16 + rm2;
            const int base = (rowa == 64) ? (64 * 84 + jl)
                                          : (rowa * 84 + 15 + jl - (rm2 & 15));
            pv = bf2f((unsigned short)T[base]);
          }
          const float p = exp2f((cacc[qt][r] + pv) * 0.18033688f);
          lsum[qt] += p;
          pf[qt][r] = (short)f2bf(p);
        }
      }
    }
    // PV: K=16 MFMA, P in A-frag layout; V B-frag = wave's k-slice (swizzled).
#pragma unroll
    for (int dt = 0; dt < 4; ++dt) {
      const bf16x4 vf = *(const bf16x4*)&Vs[(dt * 16 + lm) * 64 + ve];
      oacc[0][dt] = __builtin_amdgcn_mfma_f32_16x16x16bf16_1k(pf[0], vf, oacc[0][dt], 0, 0, 0);
      oacc[1][dt] = __builtin_amdgcn_mfma_f32_16x16x16bf16_1k(pf[1], vf, oacc[1][dt], 0, 0, 0);
    }
  }
  // Epilogue: reduce k-slice partials across the 4 wk-waves of each q-half.
#pragma unroll
  for (int qt = 0; qt < 2; ++qt) {  // sum the 4 lq lanes (k within slice)
    lsum[qt] += __shfl_xor(lsum[qt], 16, 64);
    lsum[qt] += __shfl_xor(lsum[qt], 32, 64);
  }
  __syncthreads();  // PV done; stray DMAs drained; Ored alias safe
  if (wk == 0) {
#pragma unroll
    for (int qt = 0; qt < 2; ++qt) {
      const int qc = (h * 2 + qt) * 16;
#pragma unroll
      for (int dt = 0; dt < 4; ++dt)
        *(f32x4*)&Ored[(dt * 16 + lm) * 68 + qc + lq * 4] = oacc[qt][dt];
      if (lq == 0) Ored[64 * 68 + qc + lm] = lsum[qt];
    }
  }
  __syncthreads();
#pragma unroll 1
  for (int r = 1; r < 4; ++r) {
    if (wk == r) {
#pragma unroll
      for (int qt = 0; qt < 2; ++qt) {
        const int qc = (h * 2 + qt) * 16;
#pragma unroll
        for (int dt = 0; dt < 4; ++dt) {
          f32x4 o = *(const f32x4*)&Ored[(dt * 16 + lm) * 68 + qc + lq * 4];
          o += oacc[qt][dt];
          *(f32x4*)&Ored[(dt * 16 + lm) * 68 + qc + lq * 4] = o;
        }
        if (lq == 0) Ored[64 * 68 + qc + lm] += lsum[qt];
      }
    }
    __syncthreads();
  }
  if (w < 4) {  // waves 0..3 write q-stripes w
    const int b = bh >> 3, hh = bh & 7;
    const f32x4 lv = *(const f32x4*)&Ored[64 * 68 + w * 16 + lq * 4];
    f32x4 inv;
#pragma unroll
    for (int r = 0; r < 4; ++r) inv[r] = 1.f / lv[r];
#pragma unroll
    for (int dt = 0; dt < 4; ++dt) {
      const f32x4 o = *(const f32x4*)&Ored[(dt * 16 + lm) * 68 + w * 16 + lq * 4];
#pragma unroll
      for (int r = 0; r < 4; ++r)
        og[((size_t)b * 2048 + i0 + w * 16 + lq * 4 + r) * 512 + hh * 64 + dt * 16 + lm] =
            f2bf(o[r] * inv[r]);
    }
  }
}

// out = O @ Wproj^T + bproj, 64x128 tiles -> grid (4,64) = 256 blocks = 1/CU.
__global__ __launch_bounds__(256) void k_gemm_proj(const unsigned short* __restrict__ og,
    const unsigned short* __restrict__ wjb, const float* __restrict__ bproj,
    float* __restrict__ out) {
  __shared__ short Asl[64 * 64], Wsl[128 * 64];
  f32x4 acc[4][2];
  const int m0 = blockIdx.y * 64, cc0 = blockIdx.x * 128;
  const unsigned short* Arow = og + (size_t)m0 * 512;
  const unsigned short* Wrow = wjb + (size_t)cc0 * 512;
  const int tid = threadIdx.x, w = tid >> 6, lane = tid & 63, lm = lane & 15, lq = lane >> 4;
  const int lrow = lane >> 3;
  const int gcol = (((lane & 7) ^ lrow) * 8);
#pragma unroll
  for (int mt = 0; mt < 4; ++mt)
#pragma unroll
    for (int nt = 0; nt < 2; ++nt) acc[mt][nt] = (f32x4){0.f, 0.f, 0.f, 0.f};
#pragma unroll 1
  for (int kc = 0; kc < 512; kc += 64) {
    __syncthreads();
#pragma unroll
    for (int ld = 0; ld < 2; ++ld) {  // A: 64 rows (16/wave)
      const int rbase = w * 16 + ld * 8;
      gload16(&Arow[(size_t)(rbase + lrow) * 512 + kc + gcol], &Asl[rbase * 64]);
    }
#pragma unroll
    for (int ld = 0; ld < 4; ++ld) {  // W: 128 rows (32/wave)
      const int rbase = w * 32 + ld * 8;
      gload16(&Wrow[(size_t)(rbase + lrow) * 512 + kc + gcol], &Wsl[rbase * 64]);
    }
    __syncthreads();
#pragma unroll
    for (int kk = 0; kk < 2; ++kk) {
      const int pcs = ((kk * 4 + lq) ^ (lm & 7)) * 8;
      bf16x8 af[4], bfr[2];
#pragma unroll
      for (int mt = 0; mt < 4; ++mt)
        af[mt] = *(const bf16x8*)&Asl[(mt * 16 + lm) * 64 + pcs];
#pragma unroll
      for (int nt = 0; nt < 2; ++nt)
        bfr[nt] = *(const bf16x8*)&Wsl[(w * 32 + nt * 16 + lm) * 64 + pcs];
#pragma unroll
      for (int mt = 0; mt < 4; ++mt)
#pragma unroll
        for (int nt = 0; nt < 2; ++nt)
          acc[mt][nt] = __builtin_amdgcn_mfma_f32_16x16x32_bf16(af[mt], bfr[nt], acc[mt][nt], 0, 0, 0);
    }
  }
#pragma unroll
  for (int nt = 0; nt < 2; ++nt) {
    const int cc = cc0 + w * 32 + nt * 16 + lm;
    const float bias = bproj[cc];
#pragma unroll
    for (int mt = 0; mt < 4; ++mt) {
#pragma unroll
      for (int r = 0; r < 4; ++r) {
        const int m = m0 + mt * 16 + lq * 4 + r;
        out[(size_t)m * 512 + cc] = acc[mt][nt][r] + bias;
      }
    }
  }
}

extern "C" void kernel_launch(void* const* d_in, const int* in_sizes, int n_in,
                              void* d_out, int out_size, void* d_ws, size_t ws_size,
                              hipStream_t stream) {
  const float* x     = (const float*)d_in[0];
  const float* pe    = (const float*)d_in[1];
  const float* wqkv  = (const float*)d_in[2];
  const float* wpos  = (const float*)d_in[3];
  const float* ub    = (const float*)d_in[4];
  const float* vb    = (const float*)d_in[5];
  const float* wproj = (const float*)d_in[6];
  const float* bproj = (const float*)d_in[7];
  float* out = (float*)d_out;
  unsigned short* ws = (unsigned short*)d_ws;

  const size_t SZ = (size_t)2 * 8 * 2048 * 64;  // one [B,H,N,HD] buffer (2M elems)
  unsigned short* qu   = ws;
  unsigned short* qv   = qu + SZ;
  unsigned short* kg   = qv + SZ;
  unsigned short* vt   = kg + SZ;   // [B,H,HD,N], written directly by qkvpos
  unsigned short* pos  = vt + SZ;
  unsigned short* og   = pos + SZ;
  unsigned short* cvtb = og + SZ;  // bf16: x | pe | wqkv | wpos | wproj
  unsigned short* xb   = cvtb;
  unsigned short* peb  = cvtb + 2097152;
  unsigned short* wqb  = cvtb + 4194304;
  unsigned short* wpb  = cvtb + 4980736;
  unsigned short* wjb  = cvtb + 5242880;

  dim3 blk(256);
  hipLaunchKernelGGL(k_cvt,         dim3(2688),   blk, 0, stream, x, pe, wqkv, wpos, wproj, cvtb);
  hipLaunchKernelGGL(k_gemm_qkvpos, dim3(16, 32), blk, 0, stream,
                     xb, peb, wqb, wpb, ub, vb, qu, qv, kg, vt, pos);
  hipLaunchKernelGGL(k_flash,       dim3(32, 16), dim3(512), 0, stream, qu, qv, kg, vt, pos, og);
  hipLaunchKernelGGL(k_gemm_proj,   dim3(4, 64),  blk, 0, stream, og, wjb, bproj, out);
}

// Round 14
// 188.121 us; speedup vs baseline: 1.6881x; 1.0290x over previous
//
#include <hip/hip_runtime.h>
#include <hip/hip_bf16.h>

// Problem constants: B=2, N=2048, C=512, H=8, HD=64
// Inputs fp32 (per reference); intermediates bf16 in ws; output fp32.
// R13 post-mortem: compiler-cast f2bf -> k_flash 97.7->91.8us (kept).
// R14: port R10's proven dbuf+async-staging structure into the two aux GEMM
// mainloops (short-K regime: 8 K-steps, grid-capped occupancy -> barrier
// drain dominates; m99-null doesn't apply, that was 3-blk/CU large-K).
// 1 barrier/K-step (was 2); staging for step k+1 issued right after the
// barrier, full-step latency cover. k_flash byte-identical to R13.
typedef __attribute__((ext_vector_type(8))) short bf16x8;
typedef __attribute__((ext_vector_type(4))) short bf16x4;
typedef __attribute__((ext_vector_type(4))) float f32x4;

__device__ __forceinline__ float bf2f(unsigned short u) {
  union { unsigned int i; float f; } c; c.i = ((unsigned int)u) << 16; return c.f;
}
__device__ __forceinline__ unsigned short f2bf(float x) {
  __hip_bfloat16 h = __float2bfloat16(x);  // RNE, bit-identical to manual path
  unsigned short u;
  __builtin_memcpy(&u, &h, 2);
  return u;
}
__device__ __forceinline__ unsigned int pk2(float a, float b) {
  return (unsigned int)f2bf(a) | ((unsigned int)f2bf(b) << 16);
}

__device__ __forceinline__ uint4 ld8f(const float* p) {
  const float4 a = *(const float4*)p;
  const float4 b = *(const float4*)(p + 4);
  uint4 r;
  r.x = pk2(a.x, a.y);
  r.y = pk2(a.z, a.w);
  r.z = pk2(b.x, b.y);
  r.w = pk2(b.z, b.w);
  return r;
}

// Async global->LDS, 16B per lane: HW writes lds_base + lane*16.
__device__ __forceinline__ void gload16(const unsigned short* g, short* l) {
  __builtin_amdgcn_global_load_lds((const __attribute__((address_space(1))) void*)g,
                                   (__attribute__((address_space(3))) void*)l, 16, 0, 0);
}

// fp32 -> bf16 pre-convert of x, pe, Wqkv, Wpos, Wproj (R11-proven).
__global__ __launch_bounds__(256) void k_cvt(const float* __restrict__ x,
    const float* __restrict__ pe, const float* __restrict__ wq,
    const float* __restrict__ wp, const float* __restrict__ wj,
    unsigned short* __restrict__ dst) {
  const long long i8 = ((long long)blockIdx.x * 256 + threadIdx.x) * 8;
  const float* src; long long off;
  if (i8 < 2097152)      { src = x;  off = i8; }
  else if (i8 < 4194304) { src = pe; off = i8 - 2097152; }
  else if (i8 < 4980736) { src = wq; off = i8 - 4194304; }
  else if (i8 < 5242880) { src = wp; off = i8 - 4980736; }
  else                   { src = wj; off = i8 - 5242880; }
  *(uint4*)&dst[i8] = ld8f(src + off);
}

// Coalesced epilogue via LDS transpose buffer TT[128][130] bf16 (aliases the
// GEMM staging LDS). Phase A: acc (+optional bias, fp32 add BEFORE rounding)
// -> TT[m_local][cc_local]. Phase B: uint4 rows to dst[bh][n][d].
__device__ __forceinline__ void epi_rows(const f32x4 acc[4][4], const float* __restrict__ bias,
                                         short* TT, unsigned short* __restrict__ dst,
                                         int m0, int cc0) {
  const int tid = threadIdx.x, w = tid >> 6, lane = tid & 63, lm = lane & 15, lq = lane >> 4;
  const int wm = w >> 1, wn = w & 1;
  __syncthreads();  // prior LDS use (mainloop frags / previous phase B) done
#pragma unroll
  for (int mt = 0; mt < 4; ++mt)
#pragma unroll
    for (int nt = 0; nt < 4; ++nt) {
      const int ccl = wn * 64 + nt * 16 + lm;
      const float bb = bias ? bias[(cc0 + ccl) & 511] : 0.f;
#pragma unroll
      for (int r = 0; r < 4; ++r)
        TT[(wm * 64 + mt * 16 + lq * 4 + r) * 130 + ccl] = (short)f2bf(acc[mt][nt][r] + bb);
    }
  __syncthreads();  // TT visible
#pragma unroll
  for (int rr = 0; rr < 8; ++rr) {
    const int ml = rr * 16 + (tid >> 4), ccl = (tid & 15) * 8;
    const uint4 v = *(const uint4*)&TT[ml * 130 + ccl];
    const int m = m0 + ml, b = m >> 11, n = m & 2047;
    const int cc = cc0 + ccl, hh = (cc >> 6) & 7, d = cc & 63;
    *(uint4*)&dst[((size_t)(b * 8 + hh) * 2048 + n) * 64 + d] = v;
  }
}

// Transposed epilogue for the V section: TT[m][cc] read along m, emit
// vt[bh][d][n] rows (coalesced). Fuses the old k_transpose_v kernel.
__device__ __forceinline__ void epi_cols(const f32x4 acc[4][4], short* TT,
                                         unsigned short* __restrict__ vt,
                                         int m0, int cc0) {
  const int tid = threadIdx.x, w = tid >> 6, lane = tid & 63, lm = lane & 15, lq = lane >> 4;
  const int wm = w >> 1, wn = w & 1;
  __syncthreads();
#pragma unroll
  for (int mt = 0; mt < 4; ++mt)
#pragma unroll
    for (int nt = 0; nt < 4; ++nt) {
      const int ccl = wn * 64 + nt * 16 + lm;
#pragma unroll
      for (int r = 0; r < 4; ++r)
        TT[(wm * 64 + mt * 16 + lq * 4 + r) * 130 + ccl] = (short)f2bf(acc[mt][nt][r]);
    }
  __syncthreads();
  const int b = m0 >> 11;
#pragma unroll
  for (int ss = 0; ss < 8; ++ss) {
    const int ccl = ss * 16 + (tid >> 4), mch = (tid & 15) * 8;
    alignas(16) unsigned short tmp[8];
#pragma unroll
    for (int j = 0; j < 8; ++j) tmp[j] = (unsigned short)TT[(mch + j) * 130 + ccl];
    const int cc = cc0 + ccl, hh = (cc >> 6) & 7, d = cc & 63;
    const int n = (m0 & 2047) + mch;
    *(uint4*)&vt[((size_t)(b * 8 + hh) * 64 + d) * 2048 + n] = *(const uint4*)tmp;
  }
}

// Fused 128-tile: qkv = x @ Wqkv^T (cc0 < 1536) and pos = pe @ Wpos^T.
// Mainloop: R10-style double-buffered async staging, 1 barrier/K-step.
// LDS [2][A 8192 | W 8192] shorts = 64KB; TT epilogue aliases buf0 (safe
// behind epi's leading barrier; no DMAs pending after last step).
__global__ __launch_bounds__(256) void k_gemm_qkvpos(const unsigned short* __restrict__ xb,
    const unsigned short* __restrict__ peb, const unsigned short* __restrict__ wqb,
    const unsigned short* __restrict__ wpb, const float* __restrict__ ub,
    const float* __restrict__ vb, unsigned short* __restrict__ qu,
    unsigned short* __restrict__ qv, unsigned short* __restrict__ kg,
    unsigned short* __restrict__ vt, unsigned short* __restrict__ pos) {
  __shared__ short SB[32768];
  f32x4 acc[4][4];
  const int m0 = blockIdx.y * 128, cc0 = blockIdx.x * 128;
  const unsigned short* Arow = (cc0 < 1536 ? xb : peb) + (size_t)m0 * 512;
  const unsigned short* Wrow = (cc0 < 1536) ? (wqb + (size_t)cc0 * 512)
                                            : (wpb + (size_t)(cc0 - 1536) * 512);
  const int tid = threadIdx.x, w = tid >> 6, lane = tid & 63, lm = lane & 15, lq = lane >> 4;
  const int wm = w >> 1, wn = w & 1;
  const int lrow = lane >> 3;
  const int gcol = (((lane & 7) ^ lrow) * 8);
#pragma unroll
  for (int mt = 0; mt < 4; ++mt)
#pragma unroll
    for (int nt = 0; nt < 4; ++nt) acc[mt][nt] = (f32x4){0.f, 0.f, 0.f, 0.f};
  // Prologue: stage K-step 0 into buf0.
#pragma unroll
  for (int ld = 0; ld < 4; ++ld) {
    const int rbase = w * 32 + ld * 8;
    gload16(&Arow[(size_t)(rbase + lrow) * 512 + gcol], &SB[rbase * 64]);
    gload16(&Wrow[(size_t)(rbase + lrow) * 512 + gcol], &SB[8192 + rbase * 64]);
  }
#pragma unroll 1
  for (int ks = 0; ks < 8; ++ks) {
    short* Asl = SB + (ks & 1) * 16384;
    short* Wsl = Asl + 8192;
    __syncthreads();  // staging(ks) drained+visible; prior step's frag reads done
    if (ks < 7) {     // async staging for ks+1 into the other buffer
      const int kc = (ks + 1) * 64;
      const int bo = ((ks & 1) ^ 1) * 16384;
#pragma unroll
      for (int ld = 0; ld < 4; ++ld) {
        const int rbase = w * 32 + ld * 8;
        gload16(&Arow[(size_t)(rbase + lrow) * 512 + kc + gcol], &SB[bo + rbase * 64]);
        gload16(&Wrow[(size_t)(rbase + lrow) * 512 + kc + gcol], &SB[bo + 8192 + rbase * 64]);
      }
    }
#pragma unroll
    for (int kk = 0; kk < 2; ++kk) {
      const int pcs = ((kk * 4 + lq) ^ (lm & 7)) * 8;
      bf16x8 af[4], bfr[4];
#pragma unroll
      for (int mt = 0; mt < 4; ++mt)
        af[mt] = *(const bf16x8*)&Asl[(wm * 64 + mt * 16 + lm) * 64 + pcs];
#pragma unroll
      for (int nt = 0; nt < 4; ++nt)
        bfr[nt] = *(const bf16x8*)&Wsl[(wn * 64 + nt * 16 + lm) * 64 + pcs];
#pragma unroll
      for (int mt = 0; mt < 4; ++mt)
#pragma unroll
        for (int nt = 0; nt < 4; ++nt)
          acc[mt][nt] = __builtin_amdgcn_mfma_f32_16x16x32_bf16(af[mt], bfr[nt], acc[mt][nt], 0, 0, 0);
    }
  }
  const int sec = cc0 >> 9;  // block-uniform (cc0 multiple of 128)
  if (sec == 0) {
    epi_rows(acc, ub, SB, qu, m0, cc0);
    epi_rows(acc, vb, SB, qv, m0, cc0);
  } else if (sec == 1) {
    epi_rows(acc, nullptr, SB, kg, m0, cc0);
  } else if (sec == 2) {
    epi_cols(acc, SB, vt, m0, cc0);
  } else {
    epi_rows(acc, nullptr, SB, pos, m0, cc0);
  }
}

// Fused flash attention v9 (R10, proven; R13 compiler-cast packing):
// async gload16 staging, XOR-swizzled unpadded LDS, 2 barriers/tile.
__global__ __launch_bounds__(512, 4) void k_flash(const unsigned short* __restrict__ qu,
    const unsigned short* __restrict__ qv, const unsigned short* __restrict__ kg,
    const unsigned short* __restrict__ vt, const unsigned short* __restrict__ posg,
    unsigned short* __restrict__ og) {
  // LDS (shorts): Ks[2][64][64] @0; Vs[2][64][64] @8192; Pn[128][64] @16384;
  // T[65][84] @24576. 30036 shorts = 60072 B -> 2 blocks/CU.
  __shared__ short SB[30036];
  short* KsB = SB;
  short* VsB = SB + 8192;
  short* Pn  = SB + 16384;
  short* T   = SB + 24576;
  float* Ored = (float*)SB;  // epilogue alias: [65][68] f32, row 64 = lsum
  const int tid = threadIdx.x, w = tid >> 6, lane = tid & 63, lm = lane & 15, lq = lane >> 4;
  const int wk = w & 3;   // k-slice within tile
  const int h  = w >> 2;  // q-half (stripes {2h, 2h+1})
  const int sw = w >> 1;  // T-build stripe
  const int ph = w & 1;   // T-build phase-half
  // XCD-aware remap: each XCD owns bh pair {2*xcd, 2*xcd+1}, all 32 i-tiles.
  const int hw = blockIdx.x + 32 * blockIdx.y;
  const int xcd = hw & 7, idx = hw >> 3;
  const int bh = xcd * 2 + (idx & 1);
  const int i0 = (idx >> 1) * 64;
  const size_t bhs = (size_t)bh;
  const unsigned short* qub = qu + bhs * (2048 * 64);
  const unsigned short* qvb = qv + bhs * (2048 * 64);
  const unsigned short* pob = posg + bhs * (2048 * 64);
  // Swizzled-read constants (phys chunk = logical chunk ^ (row&7)):
  const int x7 = lm & 7;
  const int kc0 = (lq ^ x7) * 8, kc1 = ((lq + 4) ^ x7) * 8;          // K & main-Pn (row&7==lm&7)
  const int xe = (lm + 7) & 7;
  const int ec0 = (lq ^ xe) * 8, ec1 = ((lq + 4) ^ xe) * 8;          // edge-Pn (slot&7==(lm-1)&7)
  const int ve = (((2 * wk + (lq >> 1)) ^ x7) * 8) + (lq & 1) * 4;   // V frag b64
  const int r0c0 = (lq ^ 7) * 8, r0c1 = ((lq + 4) ^ 7) * 8;          // eb reload (slot&7==7)
  // Staging constants (gemm's source-swizzle pattern):
  const int lrow = lane >> 3;
  const int gcol = ((lane & 7) ^ lrow) * 8;
  const unsigned short* ksrc = &kg[(bhs * 2048 + 8 * w + lrow) * 64 + gcol];
  const unsigned short* vsrc = &vt[(bhs * 64 + 8 * w + lrow) * 2048 + gcol];
  // (q+u) B-frags for this wave's two q-stripes (content scores).
  bf16x8 au[2][2];
#pragma unroll
  for (int qt = 0; qt < 2; ++qt) {
    const int qs = h * 2 + qt;
    au[qt][0] = *(const bf16x8*)&qub[(size_t)(i0 + qs * 16 + lm) * 64 + lq * 8];
    au[qt][1] = *(const bf16x8*)&qub[(size_t)(i0 + qs * 16 + lm) * 64 + 32 + lq * 8];
  }
  // (q+v) frags for T-build stripe sw, and edge rows (T row 64 = q_{i0+64}).
  const bf16x8 av0 = *(const bf16x8*)&qvb[(size_t)(i0 + sw * 16 + lm) * 64 + lq * 8];
  const bf16x8 av1 = *(const bf16x8*)&qvb[(size_t)(i0 + sw * 16 + lm) * 64 + 32 + lq * 8];
  const int rowe = min(i0 + 49 + lm, 2047);  // row 64 never read when i0==1984
  const bf16x8 ae0 = *(const bf16x8*)&qvb[(size_t)rowe * 64 + lq * 8];
  const bf16x8 ae1 = *(const bf16x8*)&qvb[(size_t)rowe * 64 + 32 + lq * 8];
  float lsum[2] = {0.f, 0.f};  // q = (h*2+qt)*16+lm, own k-slice partial
  f32x4 oacc[2][4];            // [qt][dt]: q=i0+(h*2+qt)*16+lq*4+r, d=dt*16+lm
#pragma unroll
  for (int ii = 0; ii < 2; ++ii)
#pragma unroll
    for (int jj = 0; jj < 4; ++jj) oacc[ii][jj] = (f32x4){0.f, 0.f, 0.f, 0.f};
  const int pb0 = 1983 - i0;  // === 7 mod 8 for all blocks (incl. i0=1984 -> -1)
  // Prologue: tile-0 K/V into buf0; Pn offsets 1..128 (16 aligned slabs,
  // 2/wave); eb (pos_{pb0}) direct from global for the edge col-0 lanes.
  gload16(ksrc, &KsB[w * 512]);
  gload16(vsrc, &VsB[w * 512]);
#pragma unroll
  for (int s = 0; s < 2; ++s) {
    const int u = 2 * w + s;
    const int slotb = (pb0 + 1 + 8 * u) & 127;
    const int grow = (pb0 + 1 + 8 * u + lrow + 4096) & 2047;
    gload16(&pob[(size_t)grow * 64 + gcol], &Pn[slotb * 64]);
  }
  bf16x8 eb0 = {}, eb1 = {};
  if (w == 1 && lm == 0) {
    const int g0 = (pb0 + 4096) & 2047;
    eb0 = *(const bf16x8*)&pob[(size_t)g0 * 64 + lq * 8];
    eb1 = *(const bf16x8*)&pob[(size_t)g0 * 64 + 32 + lq * 8];
  }
#pragma unroll 1
  for (int jt = 0; jt < 32; ++jt) {
    const int j0 = jt * 64;
    const int pb = pb0 + j0;
    const int nb = jt & 1;
    short* Ks = KsB + nb * 4096;
    short* Vs = VsB + nb * 4096;
    __syncthreads();  // B1: staging(jt) drained+visible; prior tile's PV reads done
    if (jt < 31) {    // async K/V staging for jt+1 into the other buffer
      const int jn = j0 + 64;
      gload16(ksrc + (size_t)jn * 64, &KsB[(nb ^ 1) * 4096 + w * 512]);
      gload16(vsrc + jn, &VsB[(nb ^ 1) * 4096 + w * 512]);
    }
    // Content scores, swapped operands: cacc[qt][r] =
    //   (q_{i0+(h*2+qt)*16+lm}+u) . K_{j0+wk*16+lq*4+r}
    const bf16x8 k0 = *(const bf16x8*)&Ks[(wk * 16 + lm) * 64 + kc0];
    const bf16x8 k1 = *(const bf16x8*)&Ks[(wk * 16 + lm) * 64 + kc1];
    f32x4 cacc[2];
#pragma unroll
    for (int qt = 0; qt < 2; ++qt) {
      cacc[qt] = __builtin_amdgcn_mfma_f32_16x16x32_bf16(k0, au[qt][0], (f32x4){0.f,0.f,0.f,0.f}, 0, 0, 0);
      cacc[qt] = __builtin_amdgcn_mfma_f32_16x16x32_bf16(k1, au[qt][1], cacc[qt], 0, 0, 0);
    }
    // T build: stripe sw rows qg=sw*16+lm over cols c=0..79, split by ph.
    // T[qg][c] = (q_{i0+qg}+v) . pos_{(pb + c + 49 - 16*sw) mod 2048}
    const int sbase = 49 - sw * 16;
    if (ph == 0) {
#pragma unroll
      for (int ct = 0; ct < 3; ++ct) {
        const int slot = (pb + sbase + ct * 16 + lm) & 127;
        const bf16x8 b0 = *(const bf16x8*)&Pn[slot * 64 + kc0];
        const bf16x8 b1 = *(const bf16x8*)&Pn[slot * 64 + kc1];
        f32x4 t0 = __builtin_amdgcn_mfma_f32_16x16x32_bf16(b0, av0, (f32x4){0.f,0.f,0.f,0.f}, 0, 0, 0);
        t0 = __builtin_amdgcn_mfma_f32_16x16x32_bf16(b1, av1, t0, 0, 0, 0);
        uint2 pk; pk.x = pk2(t0[0], t0[1]); pk.y = pk2(t0[2], t0[3]);
        *(uint2*)&T[(sw * 16 + lm) * 84 + ct * 16 + lq * 4] = pk;
      }
    } else {
#pragma unroll
      for (int ct = 3; ct < 5; ++ct) {
        const int slot = (pb + sbase + ct * 16 + lm) & 127;
        const bf16x8 b0 = *(const bf16x8*)&Pn[slot * 64 + kc0];
        const bf16x8 b1 = *(const bf16x8*)&Pn[slot * 64 + kc1];
        f32x4 t0 = __builtin_amdgcn_mfma_f32_16x16x32_bf16(b0, av0, (f32x4){0.f,0.f,0.f,0.f}, 0, 0, 0);
        t0 = __builtin_amdgcn_mfma_f32_16x16x32_bf16(b1, av1, t0, 0, 0, 0);
        uint2 pk; pk.x = pk2(t0[0], t0[1]); pk.y = pk2(t0[2], t0[3]);
        *(uint2*)&T[(sw * 16 + lm) * 84 + ct * 16 + lq * 4] = pk;
      }
      {  // edge row qg=64: T[64][c'] = (q_{i0+64}+v) . pos_{pb + c'};
         // ph1 waves cover col groups c' = sw*16 + 0..15. Col 0's pos row
         // (offset 0) comes from regs (its Pn slot was clobbered last tile).
        bf16x8 b0, b1;
        if (sw == 0 && lm == 0) {
          b0 = eb0; b1 = eb1;
        } else {
          const int slot = (pb + sw * 16 + lm) & 127;
          b0 = *(const bf16x8*)&Pn[slot * 64 + ec0];
          b1 = *(const bf16x8*)&Pn[slot * 64 + ec1];
        }
        f32x4 e0 = __builtin_amdgcn_mfma_f32_16x16x32_bf16(b0, ae0, (f32x4){0.f,0.f,0.f,0.f}, 0, 0, 0);
        e0 = __builtin_amdgcn_mfma_f32_16x16x32_bf16(b1, ae1, e0, 0, 0, 0);
        if (lm == 15) {
          uint2 pk; pk.x = pk2(e0[0], e0[1]); pk.y = pk2(e0[2], e0[3]);
          *(uint2*)&T[64 * 84 + sw * 16 + lq * 4] = pk;
        }
        if (sw == 0 && lm == 0) {  // reload eb = pos_{pb+64} before B2's clobber
          const int sl = (pb + 64) & 127;
          eb0 = *(const bf16x8*)&Pn[sl * 64 + r0c0];
          eb1 = *(const bf16x8*)&Pn[sl * 64 + r0c1];
        }
      }
    }
    __syncthreads();  // B2: T visible cross-wave; all Pn reads of this tile done
    if (jt < 31) {    // async Pn staging: rows pb+129..pb+192 (8 aligned slabs)
      const int slotb = (pb + 129 + 8 * w) & 127;
      const int grow = (pb + 129 + 8 * w + lrow + 4096) & 2047;
      gload16(&pob[(size_t)grow * 64 + gcol], &Pn[slotb * 64]);
    }
    // Gather pos addend + softmax-exp + in-lane bf16 pack (PV A-frags).
    const int diag = i0 - j0;
    const int jl0 = wk * 16 + lq * 4;
    bf16x4 pf[2];
    if (diag >= 64 || diag <= -128) {  // fast: delta uniform, no j==i+1
      const int du = (diag <= -128) ? 1 : 0;
      const int rm = lm + du;
#pragma unroll
      for (int qt = 0; qt < 2; ++qt) {
        const int rowa = (h * 2 + qt) * 16 + rm;
        const int base = (rowa == 64) ? (64 * 84 + jl0)
                                      : (rowa * 84 + 15 + jl0 - (rm & 15));
#pragma unroll
        for (int r = 0; r < 4; ++r) {
          const float pv = bf2f((unsigned short)T[base + r]);
          const float p = exp2f((cacc[qt][r] + pv) * 0.18033688f);
          lsum[qt] += p;
          pf[qt][r] = (short)f2bf(p);
        }
      }
    } else {  // boundary tiles (diag in {0,-64}): per-element delta/zero
#pragma unroll
      for (int qt = 0; qt < 2; ++qt) {
        const int qs = h * 2 + qt;
#pragma unroll
        for (int r = 0; r < 4; ++r) {
          const int jl = jl0 + r;
          const int d = (j0 - i0) + jl - (qs * 16 + lm);
          float pv;
          if (d == 1) {
            pv = 0.f;
          } else {
            const int rm2 = lm + ((d > 1) ? 1 : 0);
            const int rowa = qs * 16 + rm2;
            const int base = (rowa == 64) ? (64 * 84 + jl)
                                          : (rowa * 84 + 15 + jl - (rm2 & 15));
            pv = bf2f((unsigned short)T[base]);
          }
          const float p = exp2f((cacc[qt][r] + pv) * 0.18033688f);
          lsum[qt] += p;
          pf[qt][r] = (short)f2bf(p);
        }
      }
    }
    // PV: K=16 MFMA, P in A-frag layout; V B-frag = wave's k-slice (swizzled).
#pragma unroll
    for (int dt = 0; dt < 4; ++dt) {
      const bf16x4 vf = *(const bf16x4*)&Vs[(dt * 16 + lm) * 64 + ve];
      oacc[0][dt] = __builtin_amdgcn_mfma_f32_16x16x16bf16_1k(pf[0], vf, oacc[0][dt], 0, 0, 0);
      oacc[1][dt] = __builtin_amdgcn_mfma_f32_16x16x16bf16_1k(pf[1], vf, oacc[1][dt], 0, 0, 0);
    }
  }
  // Epilogue: reduce k-slice partials across the 4 wk-waves of each q-half.
#pragma unroll
  for (int qt = 0; qt < 2; ++qt) {  // sum the 4 lq lanes (k within slice)
    lsum[qt] += __shfl_xor(lsum[qt], 16, 64);
    lsum[qt] += __shfl_xor(lsum[qt], 32, 64);
  }
  __syncthreads();  // PV done; stray DMAs drained; Ored alias safe
  if (wk == 0) {
#pragma unroll
    for (int qt = 0; qt < 2; ++qt) {
      const int qc = (h * 2 + qt) * 16;
#pragma unroll
      for (int dt = 0; dt < 4; ++dt)
        *(f32x4*)&Ored[(dt * 16 + lm) * 68 + qc + lq * 4] = oacc[qt][dt];
      if (lq == 0) Ored[64 * 68 + qc + lm] = lsum[qt];
    }
  }
  __syncthreads();
#pragma unroll 1
  for (int r = 1; r < 4; ++r) {
    if (wk == r) {
#pragma unroll
      for (int qt = 0; qt < 2; ++qt) {
        const int qc = (h * 2 + qt) * 16;
#pragma unroll
        for (int dt = 0; dt < 4; ++dt) {
          f32x4 o = *(const f32x4*)&Ored[(dt * 16 + lm) * 68 + qc + lq * 4];
          o += oacc[qt][dt];
          *(f32x4*)&Ored[(dt * 16 + lm) * 68 + qc + lq * 4] = o;
        }
        if (lq == 0) Ored[64 * 68 + qc + lm] += lsum[qt];
      }
    }
    __syncthreads();
  }
  if (w < 4) {  // waves 0..3 write q-stripes w
    const int b = bh >> 3, hh = bh & 7;
    const f32x4 lv = *(const f32x4*)&Ored[64 * 68 + w * 16 + lq * 4];
    f32x4 inv;
#pragma unroll
    for (int r = 0; r < 4; ++r) inv[r] = 1.f / lv[r];
#pragma unroll
    for (int dt = 0; dt < 4; ++dt) {
      const f32x4 o = *(const f32x4*)&Ored[(dt * 16 + lm) * 68 + w * 16 + lq * 4];
#pragma unroll
      for (int r = 0; r < 4; ++r)
        og[((size_t)b * 2048 + i0 + w * 16 + lq * 4 + r) * 512 + hh * 64 + dt * 16 + lm] =
            f2bf(o[r] * inv[r]);
    }
  }
}

// out = O @ Wproj^T + bproj, 64x128 tiles, grid (4,64) = 256 blocks = 1/CU.
// Mainloop: R10-style double-buffered async staging, 1 barrier/K-step.
// LDS [2][A 4096 | W 8192] shorts = 48KB.
__global__ __launch_bounds__(256) void k_gemm_proj(const unsigned short* __restrict__ og,
    const unsigned short* __restrict__ wjb, const float* __restrict__ bproj,
    float* __restrict__ out) {
  __shared__ short SB[24576];
  f32x4 acc[4][2];
  const int m0 = blockIdx.y * 64, cc0 = blockIdx.x * 128;
  const unsigned short* Arow = og + (size_t)m0 * 512;
  const unsigned short* Wrow = wjb + (size_t)cc0 * 512;
  const int tid = threadIdx.x, w = tid >> 6, lane = tid & 63, lm = lane & 15, lq = lane >> 4;
  const int lrow = lane >> 3;
  const int gcol = (((lane & 7) ^ lrow) * 8);
#pragma unroll
  for (int mt = 0; mt < 4; ++mt)
#pragma unroll
    for (int nt = 0; nt < 2; ++nt) acc[mt][nt] = (f32x4){0.f, 0.f, 0.f, 0.f};
  // Prologue: stage K-step 0 into buf0.
#pragma unroll
  for (int ld = 0; ld < 2; ++ld) {  // A: 64 rows (16/wave)
    const int rbase = w * 16 + ld * 8;
    gload16(&Arow[(size_t)(rbase + lrow) * 512 + gcol], &SB[rbase * 64]);
  }
#pragma unroll
  for (int ld = 0; ld < 4; ++ld) {  // W: 128 rows (32/wave)
    const int rbase = w * 32 + ld * 8;
    gload16(&Wrow[(size_t)(rbase + lrow) * 512 + gcol], &SB[4096 + rbase * 64]);
  }
#pragma unroll 1
  for (int ks = 0; ks < 8; ++ks) {
    short* Asl = SB + (ks & 1) * 12288;
    short* Wsl = Asl + 4096;
    __syncthreads();  // staging(ks) drained+visible; prior step's frag reads done
    if (ks < 7) {     // async staging for ks+1 into the other buffer
      const int kc = (ks + 1) * 64;
      const int bo = ((ks & 1) ^ 1) * 12288;
#pragma unroll
      for (int ld = 0; ld < 2; ++ld) {
        const int rbase = w * 16 + ld * 8;
        gload16(&Arow[(size_t)(rbase + lrow) * 512 + kc + gcol], &SB[bo + rbase * 64]);
      }
#pragma unroll
      for (int ld = 0; ld < 4; ++ld) {
        const int rbase = w * 32 + ld * 8;
        gload16(&Wrow[(size_t)(rbase + lrow) * 512 + kc + gcol], &SB[bo + 4096 + rbase * 64]);
      }
    }
#pragma unroll
    for (int kk = 0; kk < 2; ++kk) {
      const int pcs = ((kk * 4 + lq) ^ (lm & 7)) * 8;
      bf16x8 af[4], bfr[2];
#pragma unroll
      for (int mt = 0; mt < 4; ++mt)
        af[mt] = *(const bf16x8*)&Asl[(mt * 16 + lm) * 64 + pcs];
#pragma unroll
      for (int nt = 0; nt < 2; ++nt)
        bfr[nt] = *(const bf16x8*)&Wsl[(w * 32 + nt * 16 + lm) * 64 + pcs];
#pragma unroll
      for (int mt = 0; mt < 4; ++mt)
#pragma unroll
        for (int nt = 0; nt < 2; ++nt)
          acc[mt][nt] = __builtin_amdgcn_mfma_f32_16x16x32_bf16(af[mt], bfr[nt], acc[mt][nt], 0, 0, 0);
    }
  }
#pragma unroll
  for (int nt = 0; nt < 2; ++nt) {
    const int cc = cc0 + w * 32 + nt * 16 + lm;
    const float bias = bproj[cc];
#pragma unroll
    for (int mt = 0; mt < 4; ++mt) {
#pragma unroll
      for (int r = 0; r < 4; ++r) {
        const int m = m0 + mt * 16 + lq * 4 + r;
        out[(size_t)m * 512 + cc] = acc[mt][nt][r] + bias;
      }
    }
  }
}

extern "C" void kernel_launch(void* const* d_in, const int* in_sizes, int n_in,
                              void* d_out, int out_size, void* d_ws, size_t ws_size,
                              hipStream_t stream) {
  const float* x     = (const float*)d_in[0];
  const float* pe    = (const float*)d_in[1];
  const float* wqkv  = (const float*)d_in[2];
  const float* wpos  = (const float*)d_in[3];
  const float* ub    = (const float*)d_in[4];
  const float* vb    = (const float*)d_in[5];
  const float* wproj = (const float*)d_in[6];
  const float* bproj = (const float*)d_in[7];
  float* out = (float*)d_out;
  unsigned short* ws = (unsigned short*)d_ws;

  const size_t SZ = (size_t)2 * 8 * 2048 * 64;  // one [B,H,N,HD] buffer (2M elems)
  unsigned short* qu   = ws;
  unsigned short* qv   = qu + SZ;
  unsigned short* kg   = qv + SZ;
  unsigned short* vt   = kg + SZ;   // [B,H,HD,N], written directly by qkvpos
  unsigned short* pos  = vt + SZ;
  unsigned short* og   = pos + SZ;
  unsigned short* cvtb = og + SZ;  // bf16: x | pe | wqkv | wpos | wproj
  unsigned short* xb   = cvtb;
  unsigned short* peb  = cvtb + 2097152;
  unsigned short* wqb  = cvtb + 4194304;
  unsigned short* wpb  = cvtb + 4980736;
  unsigned short* wjb  = cvtb + 5242880;

  dim3 blk(256);
  hipLaunchKernelGGL(k_cvt,         dim3(2688),   blk, 0, stream, x, pe, wqkv, wpos, wproj, cvtb);
  hipLaunchKernelGGL(k_gemm_qkvpos, dim3(16, 32), blk, 0, stream,
                     xb, peb, wqb, wpb, ub, vb, qu, qv, kg, vt, pos);
  hipLaunchKernelGGL(k_flash,       dim3(32, 16), dim3(512), 0, stream, qu, qv, kg, vt, pos, og);
  hipLaunchKernelGGL(k_gemm_proj,   dim3(4, 64),  blk, 0, stream, og, wjb, bproj, out);
}